// Round 4
// baseline (573.951 us; speedup 1.0000x reference)
//
#include <hip/hip_runtime.h>

// ROUND 4 = ATTRIBUTION PROBE: exact round-1 source (492.5 us measured),
// with the pre-layer group [init,bin,bexc,csr] and [prep,gemm1m] each
// launched TWICE. dur delta vs 492.5 = that group's total time.

#define HIDDEN 64
#define IN_DIM 512
#define CAP 4096      // bucket capacity (mean load ~2046 for E=1.6M over 782 buckets; 45 sigma headroom)
#define NB_MAX 1024   // max buckets (n_nodes <= 131072)

typedef short v8s __attribute__((ext_vector_type(8)));
typedef float v4f __attribute__((ext_vector_type(4)));

static __device__ __forceinline__ unsigned short f2bf(float f) {
    unsigned int u = __float_as_uint(f);
    u = (u + 0x7FFF + ((u >> 16) & 1)) >> 16;   // RNE
    return (unsigned short)u;
}
static __device__ __forceinline__ float bf2f(unsigned short u) {
    return __uint_as_float(((unsigned int)u) << 16);
}
static __device__ __forceinline__ float bflo(unsigned u) { return __uint_as_float(u << 16); }
static __device__ __forceinline__ float bfhi(unsigned u) { return __uint_as_float(u & 0xffff0000u); }

// ---------------- init: zero bucket cursors + pool accumulators ------------
__global__ void k_init(int* cursor, float* gsum, int* gcnt) {
    int i = blockIdx.x * 256 + threadIdx.x;
    if (i < NB_MAX) cursor[i] = 0;
    if (i < 256) { gsum[i] = 0.f; gcnt[i] = 0; }
}

// ---------------- bin edges by dst>>7 into fixed-stride buckets ------------
// word = (src<<7) | (dst&127). LDS histogram -> one global atomic per
// (block,bin) -> LDS-slotted writes (short contiguous runs, low write-amp).
__launch_bounds__(256)
__global__ void k_bin(const int* __restrict__ src, const int* __restrict__ dst,
                      int* cursor, unsigned* __restrict__ bucket_data, int n_edges) {
    __shared__ unsigned words[4096];          // 16 KB
    __shared__ unsigned short binsh[4096];    // 8 KB
    __shared__ int hist[NB_MAX];              // 4 KB
    __shared__ int base[NB_MAX];              // 4 KB
    const int tid = threadIdx.x;
    const int e0 = blockIdx.x * 4096;
    for (int i = tid; i < NB_MAX; i += 256) hist[i] = 0;
    __syncthreads();
    for (int i = tid; i < 4096; i += 256) {
        int e = e0 + i;
        if (e < n_edges) {
            int d = dst[e], s = src[e];
            words[i] = ((unsigned)s << 7) | (unsigned)(d & 127);
            int b = d >> 7;
            binsh[i] = (unsigned short)b;
            atomicAdd(&hist[b], 1);
        } else binsh[i] = 0xFFFFu;
    }
    __syncthreads();
    for (int b = tid; b < NB_MAX; b += 256) {
        int c = hist[b];
        base[b] = c ? atomicAdd(&cursor[b], c) : 0;
        hist[b] = 0;
    }
    __syncthreads();
    for (int i = tid; i < 4096; i += 256) {
        unsigned short b = binsh[i];
        if (b != 0xFFFFu) {
            int slot = atomicAdd(&hist[b], 1);
            int p = base[b] + slot;
            if (p < CAP) bucket_data[(size_t)b * CAP + p] = words[i];
        }
    }
}

// ---------------- exclusive scan of bucket counts -> bucket_base -----------
__launch_bounds__(256)
__global__ void k_bexc(const int* __restrict__ cursor, int* __restrict__ bucket_base,
                       int* __restrict__ row_start, int n_nodes, int nbuck) {
    __shared__ int wsum[4];
    const int t = threadIdx.x, lane = t & 63, w = t >> 6;
    int v[4], s = 0;
#pragma unroll
    for (int k = 0; k < 4; ++k) {
        int i = t * 4 + k;
        int c = (i < nbuck) ? cursor[i] : 0;
        if (c > CAP) c = CAP;
        v[k] = s; s += c;
    }
    int inc = s;
#pragma unroll
    for (int off = 1; off < 64; off <<= 1) {
        int u = __shfl_up(inc, off, 64);
        if (lane >= off) inc += u;
    }
    if (lane == 63) wsum[w] = inc;
    __syncthreads();
    int cross = 0;
    for (int i = 0; i < w; ++i) cross += wsum[i];
    int b0 = cross + inc - s;
#pragma unroll
    for (int k = 0; k < 4; ++k) {
        int i = t * 4 + k;
        if (i < NB_MAX) bucket_base[i] = b0 + v[k];
    }
    if (t == 255) row_start[n_nodes] = cross + inc;   // total kept edges
}

// ---------------- per-bucket CSR build (coalesced, local LDS) --------------
// block = bucket: count 128 local degrees, local scan, place edges into the
// bucket's contiguous csr region. Also emits row_start and dinv.
__launch_bounds__(256)
__global__ void k_csr(const unsigned* __restrict__ bucket_data, const int* __restrict__ cursor,
                      const int* __restrict__ bucket_base,
                      int* __restrict__ row_start, int* __restrict__ csr,
                      float* __restrict__ dinv, int n_nodes) {
    __shared__ unsigned words[CAP];   // 16 KB
    __shared__ int cnt[128];
    __shared__ int loff[128];
    __shared__ int cur[128];
    __shared__ int w0sum;
    const int tid = threadIdx.x, bin = blockIdx.x, n0 = bin << 7;
    int c = cursor[bin]; if (c > CAP) c = CAP;
    const unsigned* bd = bucket_data + (size_t)bin * CAP;
    for (int i = tid; i < c; i += 256) words[i] = bd[i];
    if (tid < 128) { cnt[tid] = 0; cur[tid] = 0; }
    __syncthreads();
    for (int i = tid; i < c; i += 256) atomicAdd(&cnt[words[i] & 127], 1);
    __syncthreads();
    int val = 0, inc = 0;
    if (tid < 128) {
        const int lane = tid & 63;
        val = cnt[tid];
        inc = val;
#pragma unroll
        for (int off = 1; off < 64; off <<= 1) {
            int u = __shfl_up(inc, off, 64);
            if (lane >= off) inc += u;
        }
        if (tid == 63) w0sum = inc;
    }
    __syncthreads();
    if (tid < 128) {
        int excl = inc - val + ((tid >= 64) ? w0sum : 0);
        loff[tid] = excl;
        int n = n0 + tid;
        if (n < n_nodes) {
            row_start[n] = bucket_base[bin] + excl;
            dinv[n] = rsqrtf((float)(val + 1));   // +1 self loop
        }
    }
    __syncthreads();
    const int gbase = bucket_base[bin];
    for (int i = tid; i < c; i += 256) {
        unsigned wd = words[i];
        int d = wd & 127;
        int slot = atomicAdd(&cur[d], 1);
        csr[gbase + loff[d] + slot] = (int)(wd >> 7);
    }
}

// ---------------- W1 -> Wt bf16 transpose [64][512] ------------------------
__global__ void k_prep(const float* __restrict__ W1, unsigned short* __restrict__ Wt) {
    int idx = blockIdx.x * 256 + threadIdx.x;
    int n = idx >> 9, k = idx & 511;
    Wt[(size_t)n * 512 + k] = f2bf(W1[(size_t)k * 64 + n]);
}

// ---------------- GEMM1 (MFMA bf16): s1 = bf16(dinv .* (x @ W1)) -----------
__launch_bounds__(256)
__global__ void k_gemm1m(const float* __restrict__ x, const unsigned short* __restrict__ Wt,
                         const float* __restrict__ dinv, unsigned short* __restrict__ s1,
                         int n_nodes) {
    __shared__ __align__(16) unsigned short lX[64 * 136];
    __shared__ __align__(16) unsigned short lW[64 * 136];
    const int tid  = threadIdx.x;
    const int lane = tid & 63;
    const int w    = tid >> 6;
    const int quad = lane >> 4;
    const int m16  = lane & 15;
    const int row0 = blockIdx.x * 64;

    v4f acc[4];
#pragma unroll
    for (int b = 0; b < 4; ++b) acc[b] = (v4f){0.f, 0.f, 0.f, 0.f};

    for (int kc = 0; kc < IN_DIM; kc += 128) {
        __syncthreads();
#pragma unroll
        for (int i = 0; i < 8; ++i) {
            int fidx = tid + i * 256;
            int r  = fidx >> 5;
            int c4 = fidx & 31;
            int gr = row0 + r;
            float4 v = make_float4(0.f, 0.f, 0.f, 0.f);
            if (gr < n_nodes) v = ((const float4*)(x + (size_t)gr * IN_DIM + kc))[c4];
            ushort4 u = make_ushort4(f2bf(v.x), f2bf(v.y), f2bf(v.z), f2bf(v.w));
            *(ushort4*)(lX + r * 136 + c4 * 4) = u;
        }
#pragma unroll
        for (int i = 0; i < 4; ++i) {
            int idx = tid + i * 256;
            int n  = idx >> 4;
            int c8 = idx & 15;
            uint4 u = *(const uint4*)(Wt + (size_t)n * 512 + kc + c8 * 8);
            *(uint4*)(lW + n * 136 + c8 * 8) = u;
        }
        __syncthreads();
#pragma unroll
        for (int kk = 0; kk < 128; kk += 32) {
            v8s a = *(const v8s*)(lX + (w * 16 + m16) * 136 + kk + quad * 8);
#pragma unroll
            for (int b = 0; b < 4; ++b) {
                v8s bb = *(const v8s*)(lW + (b * 16 + m16) * 136 + kk + quad * 8);
                acc[b] = __builtin_amdgcn_mfma_f32_16x16x32_bf16(a, bb, acc[b], 0, 0, 0);
            }
        }
    }
    __syncthreads();
    float* lC = (float*)lX;
#pragma unroll
    for (int b = 0; b < 4; ++b)
#pragma unroll
        for (int r = 0; r < 4; ++r) {
            int rowt = w * 16 + quad * 4 + r;
            lC[rowt * 65 + b * 16 + m16] = acc[b][r];
        }
    __syncthreads();
#pragma unroll
    for (int i = 0; i < 2; ++i) {
        int base = i * 2048 + tid * 8;
        int r = base >> 6;
        int c = base & 63;
        int gr = row0 + r;
        if (gr < n_nodes) {
            float d = dinv[gr];
            const float* p = lC + r * 65 + c;
            unsigned p0 = (unsigned)f2bf(p[0] * d) | ((unsigned)f2bf(p[1] * d) << 16);
            unsigned p1 = (unsigned)f2bf(p[2] * d) | ((unsigned)f2bf(p[3] * d) << 16);
            unsigned p2 = (unsigned)f2bf(p[4] * d) | ((unsigned)f2bf(p[5] * d) << 16);
            unsigned p3 = (unsigned)f2bf(p[6] * d) | ((unsigned)f2bf(p[7] * d) << 16);
            *(uint4*)(s1 + (size_t)gr * 64 + c) = make_uint4(p0, p1, p2, p3);
        }
    }
}

// ---------------- layer1: packed CSR gather + finalize + GEMM2 -------------
#define NPW 4   // nodes per wave

__launch_bounds__(256)
__global__ void k_layer1(const unsigned short* __restrict__ sin, const int* __restrict__ row_start,
                         const int* __restrict__ csr, const float* __restrict__ W2,
                         const float* __restrict__ b1, const float* __restrict__ dinv,
                         unsigned short* __restrict__ sout, int n_nodes) {
    __shared__ float ldsW[HIDDEN * HIDDEN];   // [k][f] 16 KB
    const int tid = threadIdx.x;
    {
        const float4* Wg = (const float4*)W2;
        float4* Wl = (float4*)ldsW;
#pragma unroll
        for (int i = 0; i < 4; ++i) Wl[tid + i * 256] = Wg[tid + i * 256];
    }
    __syncthreads();
    const int lane = tid & 63;
    const int wave = tid >> 6;
    const int g = lane >> 4;
    const int l = lane & 15;
    const float4 b4 = ((const float4*)b1)[l];
    const int n0 = (blockIdx.x * 4 + wave) * NPW;
    if (n0 >= n_nodes) return;

    // prime the pipeline for node n0
    int rs_nxt = row_start[n0];
    int idx_nxt = csr[rs_nxt + lane];
    uint2 us_nxt = *(const uint2*)(sin + (size_t)n0 * HIDDEN + l * 4);

    for (int i = 0; i < NPW; ++i) {
        int n = n0 + i;
        if (n >= n_nodes) break;
        const int rs = rs_nxt;
        const int re = row_start[n + 1];
        const int idx = idx_nxt;
        const uint2 uself = us_nxt;
        // issue next node's first-hop loads before this node's gather
        if (i + 1 < NPW && n + 1 < n_nodes) {
            rs_nxt = re;
            idx_nxt = csr[re + lane];
            us_nxt = *(const uint2*)(sin + (size_t)(n + 1) * HIDDEN + l * 4);
        }

        float4 acc = make_float4(0.f, 0.f, 0.f, 0.f);   // group-partial
        int m0 = re - rs; if (m0 > 64) m0 = 64;
        int mq = (m0 + 3) >> 2;
#pragma unroll 4
        for (int jq = 0; jq < mq; ++jq) {
            int myj = jq * 4 + g;
            int cm = myj < m0 ? myj : 0;            // clamp: load always valid
            int a = __shfl(idx, cm, 64);
            uint2 u = *(const uint2*)(sin + (size_t)a * HIDDEN + l * 4);
            if (myj < m0) {
                acc.x += bflo(u.x); acc.y += bfhi(u.x);
                acc.z += bflo(u.y); acc.w += bfhi(u.y);
            }
        }
        if (__builtin_expect(re - rs > 64, 0)) {
            for (int base = rs + 64; base < re; base += 64) {
                int idx2 = csr[base + lane];
                int m = re - base; if (m > 64) m = 64;
                int mq2 = (m + 3) >> 2;
#pragma unroll 4
                for (int jq = 0; jq < mq2; ++jq) {
                    int myj = jq * 4 + g;
                    int cm = myj < m ? myj : 0;
                    int a = __shfl(idx2, cm, 64);
                    uint2 u = *(const uint2*)(sin + (size_t)a * HIDDEN + l * 4);
                    if (myj < m) {
                        acc.x += bflo(u.x); acc.y += bfhi(u.x);
                        acc.z += bflo(u.y); acc.w += bfhi(u.y);
                    }
                }
            }
        }
        acc.x += __shfl_xor(acc.x, 16, 64); acc.y += __shfl_xor(acc.y, 16, 64);
        acc.z += __shfl_xor(acc.z, 16, 64); acc.w += __shfl_xor(acc.w, 16, 64);
        acc.x += __shfl_xor(acc.x, 32, 64); acc.y += __shfl_xor(acc.y, 32, 64);
        acc.z += __shfl_xor(acc.z, 32, 64); acc.w += __shfl_xor(acc.w, 32, 64);
        acc.x += bflo(uself.x); acc.y += bfhi(uself.x);
        acc.z += bflo(uself.y); acc.w += bfhi(uself.y);
        float d = dinv[n];
        float4 h;
        h.x = fmaxf(fmaf(d, acc.x, b4.x), 0.f);
        h.y = fmaxf(fmaf(d, acc.y, b4.y), 0.f);
        h.z = fmaxf(fmaf(d, acc.z, b4.z), 0.f);
        h.w = fmaxf(fmaf(d, acc.w, b4.w), 0.f);
        // GEMM2, k-partitioned: group g handles k = 16g..16g+15
        float4 a4 = make_float4(0.f, 0.f, 0.f, 0.f);
#pragma unroll
        for (int kk = 0; kk < 16; ++kk) {
            int srcl = 4 * g + (kk >> 2);
            float hk;
            if ((kk & 3) == 0)      hk = __shfl(h.x, srcl, 64);
            else if ((kk & 3) == 1) hk = __shfl(h.y, srcl, 64);
            else if ((kk & 3) == 2) hk = __shfl(h.z, srcl, 64);
            else                    hk = __shfl(h.w, srcl, 64);
            float4 w4 = *(const float4*)(ldsW + (16 * g + kk) * HIDDEN + 4 * l);
            a4.x = fmaf(hk, w4.x, a4.x);
            a4.y = fmaf(hk, w4.y, a4.y);
            a4.z = fmaf(hk, w4.z, a4.z);
            a4.w = fmaf(hk, w4.w, a4.w);
        }
        a4.x += __shfl_xor(a4.x, 16, 64); a4.y += __shfl_xor(a4.y, 16, 64);
        a4.z += __shfl_xor(a4.z, 16, 64); a4.w += __shfl_xor(a4.w, 16, 64);
        a4.x += __shfl_xor(a4.x, 32, 64); a4.y += __shfl_xor(a4.y, 32, 64);
        a4.z += __shfl_xor(a4.z, 32, 64); a4.w += __shfl_xor(a4.w, 32, 64);
        if (g == 0) {
            unsigned p0 = (unsigned)f2bf(a4.x * d) | ((unsigned)f2bf(a4.y * d) << 16);
            unsigned p1 = (unsigned)f2bf(a4.z * d) | ((unsigned)f2bf(a4.w * d) << 16);
            *(uint2*)(sout + (size_t)n * HIDDEN + l * 4) = make_uint2(p0, p1);
        }
    }
}

// ---------------- layer2: packed CSR gather + finalize + Wfc dot + pool ----
__launch_bounds__(256)
__global__ void k_layer2pool(const unsigned short* __restrict__ sin, const int* __restrict__ row_start,
                             const int* __restrict__ csr, const float* __restrict__ b2,
                             const float* __restrict__ dinv, const float* __restrict__ Wfc,
                             const int* __restrict__ batch,
                             float* gsum, int* gcnt, int n_nodes) {
    __shared__ float lsum[256];
    __shared__ int   lcnt[256];
    const int tid = threadIdx.x;
    lsum[tid] = 0.f; lcnt[tid] = 0;
    __syncthreads();
    const int lane = tid & 63;
    const int wave = tid >> 6;
    const int g = lane >> 4;
    const int l = lane & 15;
    const float4 b4  = ((const float4*)b2)[l];
    const float4 wf4 = ((const float4*)Wfc)[l];
    const int n0 = (blockIdx.x * 4 + wave) * NPW;
    if (n0 < n_nodes) {
        // prime the pipeline for node n0
        int rs_nxt = row_start[n0];
        int idx_nxt = csr[rs_nxt + lane];
        uint2 us_nxt = *(const uint2*)(sin + (size_t)n0 * HIDDEN + l * 4);

        for (int i = 0; i < NPW; ++i) {
            int n = n0 + i;
            if (n >= n_nodes) break;
            const int rs = rs_nxt;
            const int re = row_start[n + 1];
            const int idx = idx_nxt;
            const uint2 uself = us_nxt;
            if (i + 1 < NPW && n + 1 < n_nodes) {
                rs_nxt = re;
                idx_nxt = csr[re + lane];
                us_nxt = *(const uint2*)(sin + (size_t)(n + 1) * HIDDEN + l * 4);
            }

            float4 acc = make_float4(0.f, 0.f, 0.f, 0.f);
            int m0 = re - rs; if (m0 > 64) m0 = 64;
            int mq = (m0 + 3) >> 2;
#pragma unroll 4
            for (int jq = 0; jq < mq; ++jq) {
                int myj = jq * 4 + g;
                int cm = myj < m0 ? myj : 0;
                int a = __shfl(idx, cm, 64);
                uint2 u = *(const uint2*)(sin + (size_t)a * HIDDEN + l * 4);
                if (myj < m0) {
                    acc.x += bflo(u.x); acc.y += bfhi(u.x);
                    acc.z += bflo(u.y); acc.w += bfhi(u.y);
                }
            }
            if (__builtin_expect(re - rs > 64, 0)) {
                for (int base = rs + 64; base < re; base += 64) {
                    int idx2 = csr[base + lane];
                    int m = re - base; if (m > 64) m = 64;
                    int mq2 = (m + 3) >> 2;
#pragma unroll 4
                    for (int jq = 0; jq < mq2; ++jq) {
                        int myj = jq * 4 + g;
                        int cm = myj < m ? myj : 0;
                        int a = __shfl(idx2, cm, 64);
                        uint2 u = *(const uint2*)(sin + (size_t)a * HIDDEN + l * 4);
                        if (myj < m) {
                            acc.x += bflo(u.x); acc.y += bfhi(u.x);
                            acc.z += bflo(u.y); acc.w += bfhi(u.y);
                        }
                    }
                }
            }
            acc.x += __shfl_xor(acc.x, 16, 64); acc.y += __shfl_xor(acc.y, 16, 64);
            acc.z += __shfl_xor(acc.z, 16, 64); acc.w += __shfl_xor(acc.w, 16, 64);
            acc.x += __shfl_xor(acc.x, 32, 64); acc.y += __shfl_xor(acc.y, 32, 64);
            acc.z += __shfl_xor(acc.z, 32, 64); acc.w += __shfl_xor(acc.w, 32, 64);
            acc.x += bflo(uself.x); acc.y += bfhi(uself.x);
            acc.z += bflo(uself.y); acc.w += bfhi(uself.y);
            float d = dinv[n];
            float t = fmaxf(fmaf(d, acc.x, b4.x), 0.f) * wf4.x
                    + fmaxf(fmaf(d, acc.y, b4.y), 0.f) * wf4.y
                    + fmaxf(fmaf(d, acc.z, b4.z), 0.f) * wf4.z
                    + fmaxf(fmaf(d, acc.w, b4.w), 0.f) * wf4.w;
            // width-16 tree: lane 0 of group 0 gets the exact 16-lane sum
#pragma unroll
            for (int off = 8; off; off >>= 1) t += __shfl_down(t, off, 16);
            if (lane == 0) {
                int gr = batch[n];
                atomicAdd(&lsum[gr], t);
                atomicAdd(&lcnt[gr], 1);
            }
        }
    }
    __syncthreads();
    if (lcnt[tid]) {
        atomicAdd(&gsum[tid], lsum[tid]);
        atomicAdd(&gcnt[tid], lcnt[tid]);
    }
}

__global__ void k_out(const float* __restrict__ gsum, const int* __restrict__ gcnt,
                      const float* __restrict__ bfc, float* out) {
    int g = threadIdx.x;
    if (g < 256) {
        float c = (float)(gcnt[g] > 1 ? gcnt[g] : 1);
        out[g] = gsum[g] / c + bfc[0];
    }
}

// ---------------------------------------------------------------------------
extern "C" void kernel_launch(void* const* d_in, const int* in_sizes, int n_in,
                              void* d_out, int out_size, void* d_ws, size_t ws_size,
                              hipStream_t stream) {
    const float* x   = (const float*)d_in[0];
    const int*   ei  = (const int*)d_in[1];
    const int*   bat = (const int*)d_in[2];
    const float* W1  = (const float*)d_in[3];
    const float* b1  = (const float*)d_in[4];
    const float* W2  = (const float*)d_in[5];
    const float* b2  = (const float*)d_in[6];
    const float* Wfc = (const float*)d_in[7];
    const float* bfc = (const float*)d_in[8];
    float* out = (float*)d_out;

    const int n_nodes = in_sizes[2];
    const int n_edges = in_sizes[1] / 2;
    const int* src = ei;
    const int* dst = ei + n_edges;
    const int NBUCK = (n_nodes + 127) >> 7;

    char* w = (char*)d_ws;
    size_t off = 0;
    auto alloc = [&](size_t bytes) -> void* {
        void* p = w + off;
        off += (bytes + 255) & ~(size_t)255;
        return p;
    };
    float* dinv = (float*)alloc((size_t)n_nodes * sizeof(float));
    unsigned short* bufA = (unsigned short*)alloc((size_t)n_nodes * HIDDEN * 2);
    unsigned short* bufB = (unsigned short*)alloc((size_t)n_nodes * HIDDEN * 2);
    unsigned short* Wt   = (unsigned short*)alloc((size_t)HIDDEN * IN_DIM * 2);
    float* gsum = (float*)alloc(256 * sizeof(float));
    int*   gcnt = (int*)  alloc(256 * sizeof(int));
    int*   cursor      = (int*)alloc((size_t)NB_MAX * sizeof(int));
    int*   bucket_base = (int*)alloc((size_t)NB_MAX * sizeof(int));
    unsigned* bucket_data = (unsigned*)alloc((size_t)NB_MAX * CAP * sizeof(unsigned));
    int* row_start = (int*)alloc(((size_t)n_nodes + 1) * sizeof(int));
    int* csr       = (int*)alloc(((size_t)n_edges + 64) * sizeof(int));
    (void)ws_size; (void)n_in; (void)out_size;

    // --- pass 1 (duplicated for attribution: group is idempotent) ---
    hipLaunchKernelGGL(k_init, dim3(NB_MAX / 256), dim3(256), 0, stream, cursor, gsum, gcnt);
    hipLaunchKernelGGL(k_bin, dim3((n_edges + 4095) / 4096), dim3(256), 0, stream,
                       src, dst, cursor, bucket_data, n_edges);
    hipLaunchKernelGGL(k_bexc, dim3(1), dim3(256), 0, stream,
                       cursor, bucket_base, row_start, n_nodes, NBUCK);
    hipLaunchKernelGGL(k_csr, dim3(NBUCK), dim3(256), 0, stream,
                       bucket_data, cursor, bucket_base, row_start, csr, dinv, n_nodes);
    // --- pass 2 (identical results; k_init re-zeroes cursor for k_bin) ---
    hipLaunchKernelGGL(k_init, dim3(NB_MAX / 256), dim3(256), 0, stream, cursor, gsum, gcnt);
    hipLaunchKernelGGL(k_bin, dim3((n_edges + 4095) / 4096), dim3(256), 0, stream,
                       src, dst, cursor, bucket_data, n_edges);
    hipLaunchKernelGGL(k_bexc, dim3(1), dim3(256), 0, stream,
                       cursor, bucket_base, row_start, n_nodes, NBUCK);
    hipLaunchKernelGGL(k_csr, dim3(NBUCK), dim3(256), 0, stream,
                       bucket_data, cursor, bucket_base, row_start, csr, dinv, n_nodes);

    hipLaunchKernelGGL(k_prep, dim3((HIDDEN * IN_DIM) / 256), dim3(256), 0, stream, W1, Wt);
    hipLaunchKernelGGL(k_gemm1m, dim3((n_nodes + 63) / 64), dim3(256), 0, stream,
                       x, Wt, dinv, bufA, n_nodes);
    hipLaunchKernelGGL(k_prep, dim3((HIDDEN * IN_DIM) / 256), dim3(256), 0, stream, W1, Wt);
    hipLaunchKernelGGL(k_gemm1m, dim3((n_nodes + 63) / 64), dim3(256), 0, stream,
                       x, Wt, dinv, bufA, n_nodes);

    const int gb = (n_nodes + 4 * NPW - 1) / (4 * NPW);
    hipLaunchKernelGGL(k_layer1, dim3(gb), dim3(256), 0, stream,
                       bufA, row_start, csr, W2, b1, dinv, bufB, n_nodes);
    hipLaunchKernelGGL(k_layer2pool, dim3(gb), dim3(256), 0, stream,
                       bufB, row_start, csr, b2, dinv, Wfc, bat, gsum, gcnt, n_nodes);
    hipLaunchKernelGGL(k_out, dim3(1), dim3(256), 0, stream, gsum, gcnt, bfc, out);
}

// Round 5
// 473.048 us; speedup vs baseline: 1.2133x; 1.2133x over previous
//
#include <hip/hip_runtime.h>

#define HIDDEN 64
#define IN_DIM 512
#define CAP 4096      // bucket capacity (mean load ~2046 for E=1.6M over 782 buckets; 45 sigma headroom)
#define NB_MAX 1024   // max buckets (n_nodes <= 131072)

typedef short v8s __attribute__((ext_vector_type(8)));
typedef float v4f __attribute__((ext_vector_type(4)));

static __device__ __forceinline__ unsigned short f2bf(float f) {
    unsigned int u = __float_as_uint(f);
    u = (u + 0x7FFF + ((u >> 16) & 1)) >> 16;   // RNE
    return (unsigned short)u;
}
static __device__ __forceinline__ float bf2f(unsigned short u) {
    return __uint_as_float(((unsigned int)u) << 16);
}
static __device__ __forceinline__ float bflo(unsigned u) { return __uint_as_float(u << 16); }
static __device__ __forceinline__ float bfhi(unsigned u) { return __uint_as_float(u & 0xffff0000u); }

// ---------------- init: zero bucket cursors + pool accumulators ------------
__global__ void k_init(int* cursor, float* gsum, int* gcnt) {
    int i = blockIdx.x * 256 + threadIdx.x;
    if (i < NB_MAX) cursor[i] = 0;
    if (i < 256) { gsum[i] = 0.f; gcnt[i] = 0; }
}

// ---------------- bin edges by dst>>7 into fixed-stride buckets ------------
__launch_bounds__(256)
__global__ void k_bin(const int* __restrict__ src, const int* __restrict__ dst,
                      int* cursor, unsigned* __restrict__ bucket_data, int n_edges) {
    __shared__ unsigned words[4096];          // 16 KB
    __shared__ unsigned short binsh[4096];    // 8 KB
    __shared__ int hist[NB_MAX];              // 4 KB
    __shared__ int base[NB_MAX];              // 4 KB
    const int tid = threadIdx.x;
    const int e0 = blockIdx.x * 4096;
    for (int i = tid; i < NB_MAX; i += 256) hist[i] = 0;
    __syncthreads();
    for (int i = tid; i < 4096; i += 256) {
        int e = e0 + i;
        if (e < n_edges) {
            int d = dst[e], s = src[e];
            words[i] = ((unsigned)s << 7) | (unsigned)(d & 127);
            int b = d >> 7;
            binsh[i] = (unsigned short)b;
            atomicAdd(&hist[b], 1);
        } else binsh[i] = 0xFFFFu;
    }
    __syncthreads();
    for (int b = tid; b < NB_MAX; b += 256) {
        int c = hist[b];
        base[b] = c ? atomicAdd(&cursor[b], c) : 0;
        hist[b] = 0;
    }
    __syncthreads();
    for (int i = tid; i < 4096; i += 256) {
        unsigned short b = binsh[i];
        if (b != 0xFFFFu) {
            int slot = atomicAdd(&hist[b], 1);
            int p = base[b] + slot;
            if (p < CAP) bucket_data[(size_t)b * CAP + p] = words[i];
        }
    }
}

// ---------------- exclusive scan of bucket counts -> bucket_base -----------
__launch_bounds__(256)
__global__ void k_bexc(const int* __restrict__ cursor, int* __restrict__ bucket_base,
                       int* __restrict__ row_start, int n_nodes, int nbuck) {
    __shared__ int wsum[4];
    const int t = threadIdx.x, lane = t & 63, w = t >> 6;
    int v[4], s = 0;
#pragma unroll
    for (int k = 0; k < 4; ++k) {
        int i = t * 4 + k;
        int c = (i < nbuck) ? cursor[i] : 0;
        if (c > CAP) c = CAP;
        v[k] = s; s += c;
    }
    int inc = s;
#pragma unroll
    for (int off = 1; off < 64; off <<= 1) {
        int u = __shfl_up(inc, off, 64);
        if (lane >= off) inc += u;
    }
    if (lane == 63) wsum[w] = inc;
    __syncthreads();
    int cross = 0;
    for (int i = 0; i < w; ++i) cross += wsum[i];
    int b0 = cross + inc - s;
#pragma unroll
    for (int k = 0; k < 4; ++k) {
        int i = t * 4 + k;
        if (i < NB_MAX) bucket_base[i] = b0 + v[k];
    }
    if (t == 255) row_start[n_nodes] = cross + inc;   // total kept edges
}

// ---------------- per-bucket CSR build (coalesced, local LDS) --------------
__launch_bounds__(256)
__global__ void k_csr(const unsigned* __restrict__ bucket_data, const int* __restrict__ cursor,
                      const int* __restrict__ bucket_base,
                      int* __restrict__ row_start, int* __restrict__ csr,
                      float* __restrict__ dinv, int n_nodes) {
    __shared__ unsigned words[CAP];   // 16 KB
    __shared__ int cnt[128];
    __shared__ int loff[128];
    __shared__ int cur[128];
    __shared__ int w0sum;
    const int tid = threadIdx.x, bin = blockIdx.x, n0 = bin << 7;
    int c = cursor[bin]; if (c > CAP) c = CAP;
    const unsigned* bd = bucket_data + (size_t)bin * CAP;
    for (int i = tid; i < c; i += 256) words[i] = bd[i];
    if (tid < 128) { cnt[tid] = 0; cur[tid] = 0; }
    __syncthreads();
    for (int i = tid; i < c; i += 256) atomicAdd(&cnt[words[i] & 127], 1);
    __syncthreads();
    int val = 0, inc = 0;
    if (tid < 128) {
        const int lane = tid & 63;
        val = cnt[tid];
        inc = val;
#pragma unroll
        for (int off = 1; off < 64; off <<= 1) {
            int u = __shfl_up(inc, off, 64);
            if (lane >= off) inc += u;
        }
        if (tid == 63) w0sum = inc;
    }
    __syncthreads();
    if (tid < 128) {
        int excl = inc - val + ((tid >= 64) ? w0sum : 0);
        loff[tid] = excl;
        int n = n0 + tid;
        if (n < n_nodes) {
            row_start[n] = bucket_base[bin] + excl;
            dinv[n] = rsqrtf((float)(val + 1));   // +1 self loop
        }
    }
    __syncthreads();
    const int gbase = bucket_base[bin];
    for (int i = tid; i < c; i += 256) {
        unsigned wd = words[i];
        int d = wd & 127;
        int slot = atomicAdd(&cur[d], 1);
        csr[gbase + loff[d] + slot] = (int)(wd >> 7);
    }
}

// ---------------- W1,W2 -> bf16 transposed Wt [64][512], Wt2 [64][64] ------
__global__ void k_prep(const float* __restrict__ W1, const float* __restrict__ W2,
                       unsigned short* __restrict__ Wt, unsigned short* __restrict__ Wt2) {
    int idx = blockIdx.x * 256 + threadIdx.x;
    if (idx < HIDDEN * IN_DIM) {
        int n = idx >> 9, k = idx & 511;
        Wt[(size_t)n * 512 + k] = f2bf(W1[(size_t)k * 64 + n]);
    } else {
        int j = idx - HIDDEN * IN_DIM;   // 0..4095
        int n = j >> 6, k = j & 63;
        Wt2[(size_t)n * 64 + k] = f2bf(W2[(size_t)k * 64 + n]);
    }
}

// ---------------- GEMM1 (MFMA bf16): s1 = bf16(dinv .* (x @ W1)) -----------
__launch_bounds__(256)
__global__ void k_gemm1m(const float* __restrict__ x, const unsigned short* __restrict__ Wt,
                         const float* __restrict__ dinv, unsigned short* __restrict__ s1,
                         int n_nodes) {
    __shared__ __align__(16) unsigned short lX[64 * 136];
    __shared__ __align__(16) unsigned short lW[64 * 136];
    const int tid  = threadIdx.x;
    const int lane = tid & 63;
    const int w    = tid >> 6;
    const int quad = lane >> 4;
    const int m16  = lane & 15;
    const int row0 = blockIdx.x * 64;

    v4f acc[4];
#pragma unroll
    for (int b = 0; b < 4; ++b) acc[b] = (v4f){0.f, 0.f, 0.f, 0.f};

    for (int kc = 0; kc < IN_DIM; kc += 128) {
        __syncthreads();
#pragma unroll
        for (int i = 0; i < 8; ++i) {
            int fidx = tid + i * 256;
            int r  = fidx >> 5;
            int c4 = fidx & 31;
            int gr = row0 + r;
            float4 v = make_float4(0.f, 0.f, 0.f, 0.f);
            if (gr < n_nodes) v = ((const float4*)(x + (size_t)gr * IN_DIM + kc))[c4];
            ushort4 u = make_ushort4(f2bf(v.x), f2bf(v.y), f2bf(v.z), f2bf(v.w));
            *(ushort4*)(lX + r * 136 + c4 * 4) = u;
        }
#pragma unroll
        for (int i = 0; i < 4; ++i) {
            int idx = tid + i * 256;
            int n  = idx >> 4;
            int c8 = idx & 15;
            uint4 u = *(const uint4*)(Wt + (size_t)n * 512 + kc + c8 * 8);
            *(uint4*)(lW + n * 136 + c8 * 8) = u;
        }
        __syncthreads();
#pragma unroll
        for (int kk = 0; kk < 128; kk += 32) {
            v8s a = *(const v8s*)(lX + (w * 16 + m16) * 136 + kk + quad * 8);
#pragma unroll
            for (int b = 0; b < 4; ++b) {
                v8s bb = *(const v8s*)(lW + (b * 16 + m16) * 136 + kk + quad * 8);
                acc[b] = __builtin_amdgcn_mfma_f32_16x16x32_bf16(a, bb, acc[b], 0, 0, 0);
            }
        }
    }
    __syncthreads();
    float* lC = (float*)lX;
#pragma unroll
    for (int b = 0; b < 4; ++b)
#pragma unroll
        for (int r = 0; r < 4; ++r) {
            int rowt = w * 16 + quad * 4 + r;
            lC[rowt * 65 + b * 16 + m16] = acc[b][r];
        }
    __syncthreads();
#pragma unroll
    for (int i = 0; i < 2; ++i) {
        int base = i * 2048 + tid * 8;
        int r = base >> 6;
        int c = base & 63;
        int gr = row0 + r;
        if (gr < n_nodes) {
            float d = dinv[gr];
            const float* p = lC + r * 65 + c;
            unsigned p0 = (unsigned)f2bf(p[0] * d) | ((unsigned)f2bf(p[1] * d) << 16);
            unsigned p1 = (unsigned)f2bf(p[2] * d) | ((unsigned)f2bf(p[3] * d) << 16);
            unsigned p2 = (unsigned)f2bf(p[4] * d) | ((unsigned)f2bf(p[5] * d) << 16);
            unsigned p3 = (unsigned)f2bf(p[6] * d) | ((unsigned)f2bf(p[7] * d) << 16);
            *(uint4*)(s1 + (size_t)gr * 64 + c) = make_uint4(p0, p1, p2, p3);
        }
    }
}

// ---------------- agg1: pure CSR gather, t = dinv .* (sum nbrs + self) -----
// Tail-free: no LDS, no GEMM, tiny VGPR footprint -> max occupancy. The
// GEMM2 that used to be fused here moves to k_gemm2m (MFMA, BW-bound).
#define NPW 4   // nodes per wave

__launch_bounds__(256)
__global__ void k_agg1(const unsigned short* __restrict__ sin, const int* __restrict__ row_start,
                       const int* __restrict__ csr, const float* __restrict__ dinv,
                       float* __restrict__ tout, int n_nodes) {
    const int tid = threadIdx.x;
    const int lane = tid & 63;
    const int wave = tid >> 6;
    const int g = lane >> 4;
    const int l = lane & 15;
    const int n0 = (blockIdx.x * 4 + wave) * NPW;
    if (n0 >= n_nodes) return;

    // prime the pipeline for node n0
    int rs_nxt = row_start[n0];
    int idx_nxt = csr[rs_nxt + lane];
    uint2 us_nxt = *(const uint2*)(sin + (size_t)n0 * HIDDEN + l * 4);

    for (int i = 0; i < NPW; ++i) {
        int n = n0 + i;
        if (n >= n_nodes) break;
        const int rs = rs_nxt;
        const int re = row_start[n + 1];
        const int idx = idx_nxt;
        const uint2 uself = us_nxt;
        if (i + 1 < NPW && n + 1 < n_nodes) {
            rs_nxt = re;
            idx_nxt = csr[re + lane];
            us_nxt = *(const uint2*)(sin + (size_t)(n + 1) * HIDDEN + l * 4);
        }

        float4 acc = make_float4(0.f, 0.f, 0.f, 0.f);   // group-partial
        int m0 = re - rs; if (m0 > 64) m0 = 64;
        int mq = (m0 + 3) >> 2;
#pragma unroll 4
        for (int jq = 0; jq < mq; ++jq) {
            int myj = jq * 4 + g;
            int cm = myj < m0 ? myj : 0;            // clamp: load always valid
            int a = __shfl(idx, cm, 64);
            uint2 u = *(const uint2*)(sin + (size_t)a * HIDDEN + l * 4);
            if (myj < m0) {
                acc.x += bflo(u.x); acc.y += bfhi(u.x);
                acc.z += bflo(u.y); acc.w += bfhi(u.y);
            }
        }
        if (__builtin_expect(re - rs > 64, 0)) {
            for (int base = rs + 64; base < re; base += 64) {
                int idx2 = csr[base + lane];
                int m = re - base; if (m > 64) m = 64;
                int mq2 = (m + 3) >> 2;
#pragma unroll 4
                for (int jq = 0; jq < mq2; ++jq) {
                    int myj = jq * 4 + g;
                    int cm = myj < m ? myj : 0;
                    int a = __shfl(idx2, cm, 64);
                    uint2 u = *(const uint2*)(sin + (size_t)a * HIDDEN + l * 4);
                    if (myj < m) {
                        acc.x += bflo(u.x); acc.y += bfhi(u.x);
                        acc.z += bflo(u.y); acc.w += bfhi(u.y);
                    }
                }
            }
        }
        acc.x += __shfl_xor(acc.x, 16, 64); acc.y += __shfl_xor(acc.y, 16, 64);
        acc.z += __shfl_xor(acc.z, 16, 64); acc.w += __shfl_xor(acc.w, 16, 64);
        acc.x += __shfl_xor(acc.x, 32, 64); acc.y += __shfl_xor(acc.y, 32, 64);
        acc.z += __shfl_xor(acc.z, 32, 64); acc.w += __shfl_xor(acc.w, 32, 64);
        acc.x += bflo(uself.x); acc.y += bfhi(uself.x);
        acc.z += bflo(uself.y); acc.w += bfhi(uself.y);
        float d = dinv[n];
        if (g == 0) {
            float4 t4 = make_float4(d * acc.x, d * acc.y, d * acc.z, d * acc.w);
            *(float4*)(tout + (size_t)n * HIDDEN + l * 4) = t4;
        }
    }
}

// ---------------- GEMM2 (MFMA bf16): bufB = bf16(dinv .* (relu(t+b1)@W2)) --
__launch_bounds__(256)
__global__ void k_gemm2m(const float* __restrict__ tin, const unsigned short* __restrict__ Wt2,
                         const float* __restrict__ b1, const float* __restrict__ dinv,
                         unsigned short* __restrict__ sout, int n_nodes) {
    __shared__ __align__(16) unsigned short lX[64 * 136];  // staging stride 72; f32 stride-65 epilogue overlay
    __shared__ __align__(16) unsigned short lW[64 * 72];
    const int tid  = threadIdx.x;
    const int lane = tid & 63;
    const int w    = tid >> 6;
    const int quad = lane >> 4;
    const int m16  = lane & 15;
    const int row0 = blockIdx.x * 64;

    // stage A = bf16(relu(t + b1)), 64x64
#pragma unroll
    for (int i = 0; i < 4; ++i) {
        int fidx = tid + i * 256;   // 0..1023
        int r  = fidx >> 4;
        int c4 = fidx & 15;
        int gr = row0 + r;
        float4 v = make_float4(0.f, 0.f, 0.f, 0.f);
        if (gr < n_nodes) v = ((const float4*)(tin + (size_t)gr * HIDDEN))[c4];
        float4 bb = ((const float4*)b1)[c4];
        v.x = fmaxf(v.x + bb.x, 0.f);
        v.y = fmaxf(v.y + bb.y, 0.f);
        v.z = fmaxf(v.z + bb.z, 0.f);
        v.w = fmaxf(v.w + bb.w, 0.f);
        ushort4 u = make_ushort4(f2bf(v.x), f2bf(v.y), f2bf(v.z), f2bf(v.w));
        *(ushort4*)(lX + r * 72 + c4 * 4) = u;
    }
    // stage W2^T bf16, 64x64
#pragma unroll
    for (int i = 0; i < 2; ++i) {
        int idx = tid + i * 256;   // 0..511
        int n  = idx >> 3;
        int c8 = idx & 7;
        uint4 u = *(const uint4*)(Wt2 + (size_t)n * 64 + c8 * 8);
        *(uint4*)(lW + n * 72 + c8 * 8) = u;
    }
    __syncthreads();
    v4f acc[4];
#pragma unroll
    for (int b = 0; b < 4; ++b) acc[b] = (v4f){0.f, 0.f, 0.f, 0.f};
#pragma unroll
    for (int kk = 0; kk < 64; kk += 32) {
        v8s a = *(const v8s*)(lX + (w * 16 + m16) * 72 + kk + quad * 8);
#pragma unroll
        for (int b = 0; b < 4; ++b) {
            v8s bb = *(const v8s*)(lW + (b * 16 + m16) * 72 + kk + quad * 8);
            acc[b] = __builtin_amdgcn_mfma_f32_16x16x32_bf16(a, bb, acc[b], 0, 0, 0);
        }
    }
    __syncthreads();
    float* lC = (float*)lX;
#pragma unroll
    for (int b = 0; b < 4; ++b)
#pragma unroll
        for (int r = 0; r < 4; ++r) {
            int rowt = w * 16 + quad * 4 + r;
            lC[rowt * 65 + b * 16 + m16] = acc[b][r];
        }
    __syncthreads();
#pragma unroll
    for (int i = 0; i < 2; ++i) {
        int base = i * 2048 + tid * 8;
        int r = base >> 6;
        int c = base & 63;
        int gr = row0 + r;
        if (gr < n_nodes) {
            float d = dinv[gr];
            const float* p = lC + r * 65 + c;
            unsigned p0 = (unsigned)f2bf(p[0] * d) | ((unsigned)f2bf(p[1] * d) << 16);
            unsigned p1 = (unsigned)f2bf(p[2] * d) | ((unsigned)f2bf(p[3] * d) << 16);
            unsigned p2 = (unsigned)f2bf(p[4] * d) | ((unsigned)f2bf(p[5] * d) << 16);
            unsigned p3 = (unsigned)f2bf(p[6] * d) | ((unsigned)f2bf(p[7] * d) << 16);
            *(uint4*)(sout + (size_t)gr * 64 + c) = make_uint4(p0, p1, p2, p3);
        }
    }
}

// ---------------- layer2: packed CSR gather + finalize + Wfc dot + pool ----
__launch_bounds__(256)
__global__ void k_layer2pool(const unsigned short* __restrict__ sin, const int* __restrict__ row_start,
                             const int* __restrict__ csr, const float* __restrict__ b2,
                             const float* __restrict__ dinv, const float* __restrict__ Wfc,
                             const int* __restrict__ batch,
                             float* gsum, int* gcnt, int n_nodes) {
    __shared__ float lsum[256];
    __shared__ int   lcnt[256];
    const int tid = threadIdx.x;
    lsum[tid] = 0.f; lcnt[tid] = 0;
    __syncthreads();
    const int lane = tid & 63;
    const int wave = tid >> 6;
    const int g = lane >> 4;
    const int l = lane & 15;
    const float4 b4  = ((const float4*)b2)[l];
    const float4 wf4 = ((const float4*)Wfc)[l];
    const int n0 = (blockIdx.x * 4 + wave) * NPW;
    if (n0 < n_nodes) {
        // prime the pipeline for node n0
        int rs_nxt = row_start[n0];
        int idx_nxt = csr[rs_nxt + lane];
        uint2 us_nxt = *(const uint2*)(sin + (size_t)n0 * HIDDEN + l * 4);

        for (int i = 0; i < NPW; ++i) {
            int n = n0 + i;
            if (n >= n_nodes) break;
            const int rs = rs_nxt;
            const int re = row_start[n + 1];
            const int idx = idx_nxt;
            const uint2 uself = us_nxt;
            if (i + 1 < NPW && n + 1 < n_nodes) {
                rs_nxt = re;
                idx_nxt = csr[re + lane];
                us_nxt = *(const uint2*)(sin + (size_t)(n + 1) * HIDDEN + l * 4);
            }

            float4 acc = make_float4(0.f, 0.f, 0.f, 0.f);
            int m0 = re - rs; if (m0 > 64) m0 = 64;
            int mq = (m0 + 3) >> 2;
#pragma unroll 4
            for (int jq = 0; jq < mq; ++jq) {
                int myj = jq * 4 + g;
                int cm = myj < m0 ? myj : 0;
                int a = __shfl(idx, cm, 64);
                uint2 u = *(const uint2*)(sin + (size_t)a * HIDDEN + l * 4);
                if (myj < m0) {
                    acc.x += bflo(u.x); acc.y += bfhi(u.x);
                    acc.z += bflo(u.y); acc.w += bfhi(u.y);
                }
            }
            if (__builtin_expect(re - rs > 64, 0)) {
                for (int base = rs + 64; base < re; base += 64) {
                    int idx2 = csr[base + lane];
                    int m = re - base; if (m > 64) m = 64;
                    int mq2 = (m + 3) >> 2;
#pragma unroll 4
                    for (int jq = 0; jq < mq2; ++jq) {
                        int myj = jq * 4 + g;
                        int cm = myj < m ? myj : 0;
                        int a = __shfl(idx2, cm, 64);
                        uint2 u = *(const uint2*)(sin + (size_t)a * HIDDEN + l * 4);
                        if (myj < m) {
                            acc.x += bflo(u.x); acc.y += bfhi(u.x);
                            acc.z += bflo(u.y); acc.w += bfhi(u.y);
                        }
                    }
                }
            }
            acc.x += __shfl_xor(acc.x, 16, 64); acc.y += __shfl_xor(acc.y, 16, 64);
            acc.z += __shfl_xor(acc.z, 16, 64); acc.w += __shfl_xor(acc.w, 16, 64);
            acc.x += __shfl_xor(acc.x, 32, 64); acc.y += __shfl_xor(acc.y, 32, 64);
            acc.z += __shfl_xor(acc.z, 32, 64); acc.w += __shfl_xor(acc.w, 32, 64);
            acc.x += bflo(uself.x); acc.y += bfhi(uself.x);
            acc.z += bflo(uself.y); acc.w += bfhi(uself.y);
            float d = dinv[n];
            float t = fmaxf(fmaf(d, acc.x, b4.x), 0.f) * wf4.x
                    + fmaxf(fmaf(d, acc.y, b4.y), 0.f) * wf4.y
                    + fmaxf(fmaf(d, acc.z, b4.z), 0.f) * wf4.z
                    + fmaxf(fmaf(d, acc.w, b4.w), 0.f) * wf4.w;
            // width-16 tree: lane 0 of group 0 gets the exact 16-lane sum
#pragma unroll
            for (int off = 8; off; off >>= 1) t += __shfl_down(t, off, 16);
            if (lane == 0) {
                int gr = batch[n];
                atomicAdd(&lsum[gr], t);
                atomicAdd(&lcnt[gr], 1);
            }
        }
    }
    __syncthreads();
    if (lcnt[tid]) {
        atomicAdd(&gsum[tid], lsum[tid]);
        atomicAdd(&gcnt[tid], lcnt[tid]);
    }
}

__global__ void k_out(const float* __restrict__ gsum, const int* __restrict__ gcnt,
                      const float* __restrict__ bfc, float* out) {
    int g = threadIdx.x;
    if (g < 256) {
        float c = (float)(gcnt[g] > 1 ? gcnt[g] : 1);
        out[g] = gsum[g] / c + bfc[0];
    }
}

// ---------------------------------------------------------------------------
extern "C" void kernel_launch(void* const* d_in, const int* in_sizes, int n_in,
                              void* d_out, int out_size, void* d_ws, size_t ws_size,
                              hipStream_t stream) {
    const float* x   = (const float*)d_in[0];
    const int*   ei  = (const int*)d_in[1];
    const int*   bat = (const int*)d_in[2];
    const float* W1  = (const float*)d_in[3];
    const float* b1  = (const float*)d_in[4];
    const float* W2  = (const float*)d_in[5];
    const float* b2  = (const float*)d_in[6];
    const float* Wfc = (const float*)d_in[7];
    const float* bfc = (const float*)d_in[8];
    float* out = (float*)d_out;

    const int n_nodes = in_sizes[2];
    const int n_edges = in_sizes[1] / 2;
    const int* src = ei;
    const int* dst = ei + n_edges;
    const int NBUCK = (n_nodes + 127) >> 7;

    char* w = (char*)d_ws;
    size_t off = 0;
    auto alloc = [&](size_t bytes) -> void* {
        void* p = w + off;
        off += (bytes + 255) & ~(size_t)255;
        return p;
    };
    float* dinv = (float*)alloc((size_t)n_nodes * sizeof(float));
    unsigned short* bufA = (unsigned short*)alloc((size_t)n_nodes * HIDDEN * 2);
    unsigned short* bufB = (unsigned short*)alloc((size_t)n_nodes * HIDDEN * 2);
    float* tbuf = (float*)alloc((size_t)n_nodes * HIDDEN * sizeof(float));
    unsigned short* Wt   = (unsigned short*)alloc((size_t)HIDDEN * IN_DIM * 2);
    unsigned short* Wt2  = (unsigned short*)alloc((size_t)HIDDEN * HIDDEN * 2);
    float* gsum = (float*)alloc(256 * sizeof(float));
    int*   gcnt = (int*)  alloc(256 * sizeof(int));
    int*   cursor      = (int*)alloc((size_t)NB_MAX * sizeof(int));
    int*   bucket_base = (int*)alloc((size_t)NB_MAX * sizeof(int));
    unsigned* bucket_data = (unsigned*)alloc((size_t)NB_MAX * CAP * sizeof(unsigned));
    int* row_start = (int*)alloc(((size_t)n_nodes + 1) * sizeof(int));
    int* csr       = (int*)alloc(((size_t)n_edges + 64) * sizeof(int));
    (void)ws_size; (void)n_in; (void)out_size;

    hipLaunchKernelGGL(k_init, dim3(NB_MAX / 256), dim3(256), 0, stream, cursor, gsum, gcnt);
    hipLaunchKernelGGL(k_bin, dim3((n_edges + 4095) / 4096), dim3(256), 0, stream,
                       src, dst, cursor, bucket_data, n_edges);
    hipLaunchKernelGGL(k_bexc, dim3(1), dim3(256), 0, stream,
                       cursor, bucket_base, row_start, n_nodes, NBUCK);
    hipLaunchKernelGGL(k_csr, dim3(NBUCK), dim3(256), 0, stream,
                       bucket_data, cursor, bucket_base, row_start, csr, dinv, n_nodes);
    hipLaunchKernelGGL(k_prep, dim3((HIDDEN * IN_DIM + HIDDEN * HIDDEN) / 256), dim3(256), 0, stream,
                       W1, W2, Wt, Wt2);
    hipLaunchKernelGGL(k_gemm1m, dim3((n_nodes + 63) / 64), dim3(256), 0, stream,
                       x, Wt, dinv, bufA, n_nodes);
    const int gb = (n_nodes + 4 * NPW - 1) / (4 * NPW);
    hipLaunchKernelGGL(k_agg1, dim3(gb), dim3(256), 0, stream,
                       bufA, row_start, csr, dinv, tbuf, n_nodes);
    hipLaunchKernelGGL(k_gemm2m, dim3((n_nodes + 63) / 64), dim3(256), 0, stream,
                       tbuf, Wt2, b1, dinv, bufB, n_nodes);
    hipLaunchKernelGGL(k_layer2pool, dim3(gb), dim3(256), 0, stream,
                       bufB, row_start, csr, b2, dinv, Wfc, bat, gsum, gcnt, n_nodes);
    hipLaunchKernelGGL(k_out, dim3(1), dim3(256), 0, stream, gsum, gcnt, bfc, out);
}

// Round 6
// 435.497 us; speedup vs baseline: 1.3179x; 1.0862x over previous
//
#include <hip/hip_runtime.h>

#define HIDDEN 64
#define IN_DIM 512
#define CAP 4096      // bucket capacity (mean load ~2046 for E=1.6M over 782 buckets; 45 sigma headroom)
#define NB_MAX 1024   // max buckets (n_nodes <= 131072)

typedef short v8s __attribute__((ext_vector_type(8)));
typedef float v4f __attribute__((ext_vector_type(4)));

static __device__ __forceinline__ unsigned short f2bf(float f) {
    unsigned int u = __float_as_uint(f);
    u = (u + 0x7FFF + ((u >> 16) & 1)) >> 16;   // RNE
    return (unsigned short)u;
}
static __device__ __forceinline__ float bf2f(unsigned short u) {
    return __uint_as_float(((unsigned int)u) << 16);
}
static __device__ __forceinline__ float bflo(unsigned u) { return __uint_as_float(u << 16); }
static __device__ __forceinline__ float bfhi(unsigned u) { return __uint_as_float(u & 0xffff0000u); }

// ---------------- init: zero cursors + pool accumulators + sentinel rows ---
// sentinel row (index n_nodes) of bufA/bufB = zeros; guard-free gathers load
// it for padded lanes (adds exact 0.0).
__global__ void k_init(int* cursor, float* gsum, int* gcnt,
                       unsigned short* bufA, unsigned short* bufB, int n_nodes) {
    int i = blockIdx.x * 256 + threadIdx.x;
    if (i < NB_MAX) cursor[i] = 0;
    if (i < 256) { gsum[i] = 0.f; gcnt[i] = 0; }
    if (i < 64) {
        bufA[(size_t)n_nodes * 64 + i] = 0;
        bufB[(size_t)n_nodes * 64 + i] = 0;
    }
}

// ---------------- bin edges by dst>>7 into fixed-stride buckets ------------
__launch_bounds__(256)
__global__ void k_bin(const int* __restrict__ src, const int* __restrict__ dst,
                      int* cursor, unsigned* __restrict__ bucket_data, int n_edges) {
    __shared__ unsigned words[4096];          // 16 KB
    __shared__ unsigned short binsh[4096];    // 8 KB
    __shared__ int hist[NB_MAX];              // 4 KB
    __shared__ int base[NB_MAX];              // 4 KB
    const int tid = threadIdx.x;
    const int e0 = blockIdx.x * 4096;
    for (int i = tid; i < NB_MAX; i += 256) hist[i] = 0;
    __syncthreads();
    for (int i = tid; i < 4096; i += 256) {
        int e = e0 + i;
        if (e < n_edges) {
            int d = dst[e], s = src[e];
            words[i] = ((unsigned)s << 7) | (unsigned)(d & 127);
            int b = d >> 7;
            binsh[i] = (unsigned short)b;
            atomicAdd(&hist[b], 1);
        } else binsh[i] = 0xFFFFu;
    }
    __syncthreads();
    for (int b = tid; b < NB_MAX; b += 256) {
        int c = hist[b];
        base[b] = c ? atomicAdd(&cursor[b], c) : 0;
        hist[b] = 0;
    }
    __syncthreads();
    for (int i = tid; i < 4096; i += 256) {
        unsigned short b = binsh[i];
        if (b != 0xFFFFu) {
            int slot = atomicAdd(&hist[b], 1);
            int p = base[b] + slot;
            if (p < CAP) bucket_data[(size_t)b * CAP + p] = words[i];
        }
    }
}

// ---------------- exclusive scan of bucket counts -> bucket_base -----------
__launch_bounds__(256)
__global__ void k_bexc(const int* __restrict__ cursor, int* __restrict__ bucket_base,
                       int* __restrict__ row_start, int n_nodes, int nbuck) {
    __shared__ int wsum[4];
    const int t = threadIdx.x, lane = t & 63, w = t >> 6;
    int v[4], s = 0;
#pragma unroll
    for (int k = 0; k < 4; ++k) {
        int i = t * 4 + k;
        int c = (i < nbuck) ? cursor[i] : 0;
        if (c > CAP) c = CAP;
        v[k] = s; s += c;
    }
    int inc = s;
#pragma unroll
    for (int off = 1; off < 64; off <<= 1) {
        int u = __shfl_up(inc, off, 64);
        if (lane >= off) inc += u;
    }
    if (lane == 63) wsum[w] = inc;
    __syncthreads();
    int cross = 0;
    for (int i = 0; i < w; ++i) cross += wsum[i];
    int b0 = cross + inc - s;
#pragma unroll
    for (int k = 0; k < 4; ++k) {
        int i = t * 4 + k;
        if (i < NB_MAX) bucket_base[i] = b0 + v[k];
    }
    if (t == 255) row_start[n_nodes] = cross + inc;   // total kept edges
}

// ---------------- per-bucket CSR build (coalesced, local LDS) --------------
// csr entries are PRE-SCALED byte offsets (src*128) for the gather kernels.
__launch_bounds__(256)
__global__ void k_csr(const unsigned* __restrict__ bucket_data, const int* __restrict__ cursor,
                      const int* __restrict__ bucket_base,
                      int* __restrict__ row_start, int* __restrict__ csr,
                      float* __restrict__ dinv, int n_nodes) {
    __shared__ unsigned words[CAP];   // 16 KB
    __shared__ int cnt[128];
    __shared__ int loff[128];
    __shared__ int cur[128];
    __shared__ int w0sum;
    const int tid = threadIdx.x, bin = blockIdx.x, n0 = bin << 7;
    int c = cursor[bin]; if (c > CAP) c = CAP;
    const unsigned* bd = bucket_data + (size_t)bin * CAP;
    for (int i = tid; i < c; i += 256) words[i] = bd[i];
    if (tid < 128) { cnt[tid] = 0; cur[tid] = 0; }
    __syncthreads();
    for (int i = tid; i < c; i += 256) atomicAdd(&cnt[words[i] & 127], 1);
    __syncthreads();
    int val = 0, inc = 0;
    if (tid < 128) {
        const int lane = tid & 63;
        val = cnt[tid];
        inc = val;
#pragma unroll
        for (int off = 1; off < 64; off <<= 1) {
            int u = __shfl_up(inc, off, 64);
            if (lane >= off) inc += u;
        }
        if (tid == 63) w0sum = inc;
    }
    __syncthreads();
    if (tid < 128) {
        int excl = inc - val + ((tid >= 64) ? w0sum : 0);
        loff[tid] = excl;
        int n = n0 + tid;
        if (n < n_nodes) {
            row_start[n] = bucket_base[bin] + excl;
            dinv[n] = rsqrtf((float)(val + 1));   // +1 self loop
        }
    }
    __syncthreads();
    const int gbase = bucket_base[bin];
    for (int i = tid; i < c; i += 256) {
        unsigned wd = words[i];
        int d = wd & 127;
        int slot = atomicAdd(&cur[d], 1);
        csr[gbase + loff[d] + slot] = (int)(wd & 0xFFFFFF80u);  // src*128 byte offset
    }
}

// ---------------- W1,W2 -> bf16 transposed Wt [64][512], Wt2 [64][64] ------
__global__ void k_prep(const float* __restrict__ W1, const float* __restrict__ W2,
                       unsigned short* __restrict__ Wt, unsigned short* __restrict__ Wt2) {
    int idx = blockIdx.x * 256 + threadIdx.x;
    if (idx < HIDDEN * IN_DIM) {
        int n = idx >> 9, k = idx & 511;
        Wt[(size_t)n * 512 + k] = f2bf(W1[(size_t)k * 64 + n]);
    } else {
        int j = idx - HIDDEN * IN_DIM;   // 0..4095
        int n = j >> 6, k = j & 63;
        Wt2[(size_t)n * 64 + k] = f2bf(W2[(size_t)k * 64 + n]);
    }
}

// ---------------- GEMM1 (MFMA bf16): s1 = bf16(dinv .* (x @ W1)) -----------
__launch_bounds__(256)
__global__ void k_gemm1m(const float* __restrict__ x, const unsigned short* __restrict__ Wt,
                         const float* __restrict__ dinv, unsigned short* __restrict__ s1,
                         int n_nodes) {
    __shared__ __align__(16) unsigned short lX[64 * 136];
    __shared__ __align__(16) unsigned short lW[64 * 136];
    const int tid  = threadIdx.x;
    const int lane = tid & 63;
    const int w    = tid >> 6;
    const int quad = lane >> 4;
    const int m16  = lane & 15;
    const int row0 = blockIdx.x * 64;

    v4f acc[4];
#pragma unroll
    for (int b = 0; b < 4; ++b) acc[b] = (v4f){0.f, 0.f, 0.f, 0.f};

    for (int kc = 0; kc < IN_DIM; kc += 128) {
        __syncthreads();
#pragma unroll
        for (int i = 0; i < 8; ++i) {
            int fidx = tid + i * 256;
            int r  = fidx >> 5;
            int c4 = fidx & 31;
            int gr = row0 + r;
            float4 v = make_float4(0.f, 0.f, 0.f, 0.f);
            if (gr < n_nodes) v = ((const float4*)(x + (size_t)gr * IN_DIM + kc))[c4];
            ushort4 u = make_ushort4(f2bf(v.x), f2bf(v.y), f2bf(v.z), f2bf(v.w));
            *(ushort4*)(lX + r * 136 + c4 * 4) = u;
        }
#pragma unroll
        for (int i = 0; i < 4; ++i) {
            int idx = tid + i * 256;
            int n  = idx >> 4;
            int c8 = idx & 15;
            uint4 u = *(const uint4*)(Wt + (size_t)n * 512 + kc + c8 * 8);
            *(uint4*)(lW + n * 136 + c8 * 8) = u;
        }
        __syncthreads();
#pragma unroll
        for (int kk = 0; kk < 128; kk += 32) {
            v8s a = *(const v8s*)(lX + (w * 16 + m16) * 136 + kk + quad * 8);
#pragma unroll
            for (int b = 0; b < 4; ++b) {
                v8s bb = *(const v8s*)(lW + (b * 16 + m16) * 136 + kk + quad * 8);
                acc[b] = __builtin_amdgcn_mfma_f32_16x16x32_bf16(a, bb, acc[b], 0, 0, 0);
            }
        }
    }
    __syncthreads();
    float* lC = (float*)lX;
#pragma unroll
    for (int b = 0; b < 4; ++b)
#pragma unroll
        for (int r = 0; r < 4; ++r) {
            int rowt = w * 16 + quad * 4 + r;
            lC[rowt * 65 + b * 16 + m16] = acc[b][r];
        }
    __syncthreads();
#pragma unroll
    for (int i = 0; i < 2; ++i) {
        int base = i * 2048 + tid * 8;
        int r = base >> 6;
        int c = base & 63;
        int gr = row0 + r;
        if (gr < n_nodes) {
            float d = dinv[gr];
            const float* p = lC + r * 65 + c;
            unsigned p0 = (unsigned)f2bf(p[0] * d) | ((unsigned)f2bf(p[1] * d) << 16);
            unsigned p1 = (unsigned)f2bf(p[2] * d) | ((unsigned)f2bf(p[3] * d) << 16);
            unsigned p2 = (unsigned)f2bf(p[4] * d) | ((unsigned)f2bf(p[5] * d) << 16);
            unsigned p3 = (unsigned)f2bf(p[6] * d) | ((unsigned)f2bf(p[7] * d) << 16);
            *(uint4*)(s1 + (size_t)gr * 64 + c) = make_uint4(p0, p1, p2, p3);
        }
    }
}

// ---------------- agg1: group-per-node gather, t = dinv.*(sum nbrs + self) -
// 16-lane group owns one node: lane l holds features 4l..4l+3 -> NO cross-
// group reduce. Per chunk: 16 sentinel-ized csr lanes feed 16 independent
// shfl+load pairs (fully unrolled, guard-free) -> 16 loads in flight.
__launch_bounds__(256)
__global__ void k_agg1(const unsigned short* __restrict__ sin, const int* __restrict__ row_start,
                       const int* __restrict__ csr, const float* __restrict__ dinv,
                       float* __restrict__ tout, int n_nodes) {
    const int tid  = threadIdx.x;
    const int lane = tid & 63;
    const int wave = tid >> 6;
    const int g = lane >> 4;     // node slot within wave
    const int l = lane & 15;     // feature lane: floats 4l..4l+3
    const int n = (blockIdx.x * 4 + wave) * 4 + g;
    const bool valid = (n < n_nodes);
    const char* sp = (const char*)sin;
    const int SENTB = n_nodes << 7;   // sentinel zero row (byte offset)

    int rs = 0, re = 0;
    if (valid) { rs = row_start[n]; re = row_start[n + 1]; }

    // init acc with the self row (sentinel for invalid slots)
    uint2 us = *(const uint2*)(sp + (size_t)(valid ? (n << 7) : SENTB) + l * 8);
    float4 acc;
    acc.x = bflo(us.x); acc.y = bfhi(us.x);
    acc.z = bflo(us.y); acc.w = bfhi(us.y);

    for (int base = rs; base < re; base += 16) {
        int p = base + l;
        int a = (p < re) ? csr[p] : SENTB;   // sentinel-ized index lane
#pragma unroll
        for (int j = 0; j < 16; ++j) {
            int ab = __shfl(a, g * 16 + j, 64);
            uint2 u = *(const uint2*)(sp + (size_t)(unsigned)ab + l * 8);
            acc.x += bflo(u.x); acc.y += bfhi(u.x);
            acc.z += bflo(u.y); acc.w += bfhi(u.y);
        }
    }
    if (valid) {
        float d = dinv[n];
        *(float4*)(tout + (size_t)n * HIDDEN + l * 4) =
            make_float4(d * acc.x, d * acc.y, d * acc.z, d * acc.w);
    }
}

// ---------------- GEMM2 (MFMA bf16): bufB = bf16(dinv .* (relu(t+b1)@W2)) --
__launch_bounds__(256)
__global__ void k_gemm2m(const float* __restrict__ tin, const unsigned short* __restrict__ Wt2,
                         const float* __restrict__ b1, const float* __restrict__ dinv,
                         unsigned short* __restrict__ sout, int n_nodes) {
    __shared__ __align__(16) unsigned short lX[64 * 136];  // staging stride 72; f32 stride-65 epilogue overlay
    __shared__ __align__(16) unsigned short lW[64 * 72];
    const int tid  = threadIdx.x;
    const int lane = tid & 63;
    const int w    = tid >> 6;
    const int quad = lane >> 4;
    const int m16  = lane & 15;
    const int row0 = blockIdx.x * 64;

    // stage A = bf16(relu(t + b1)), 64x64
#pragma unroll
    for (int i = 0; i < 4; ++i) {
        int fidx = tid + i * 256;   // 0..1023
        int r  = fidx >> 4;
        int c4 = fidx & 15;
        int gr = row0 + r;
        float4 v = make_float4(0.f, 0.f, 0.f, 0.f);
        if (gr < n_nodes) v = ((const float4*)(tin + (size_t)gr * HIDDEN))[c4];
        float4 bb = ((const float4*)b1)[c4];
        v.x = fmaxf(v.x + bb.x, 0.f);
        v.y = fmaxf(v.y + bb.y, 0.f);
        v.z = fmaxf(v.z + bb.z, 0.f);
        v.w = fmaxf(v.w + bb.w, 0.f);
        ushort4 u = make_ushort4(f2bf(v.x), f2bf(v.y), f2bf(v.z), f2bf(v.w));
        *(ushort4*)(lX + r * 72 + c4 * 4) = u;
    }
    // stage W2^T bf16, 64x64
#pragma unroll
    for (int i = 0; i < 2; ++i) {
        int idx = tid + i * 256;   // 0..511
        int n  = idx >> 3;
        int c8 = idx & 7;
        uint4 u = *(const uint4*)(Wt2 + (size_t)n * 64 + c8 * 8);
        *(uint4*)(lW + n * 72 + c8 * 8) = u;
    }
    __syncthreads();
    v4f acc[4];
#pragma unroll
    for (int b = 0; b < 4; ++b) acc[b] = (v4f){0.f, 0.f, 0.f, 0.f};
#pragma unroll
    for (int kk = 0; kk < 64; kk += 32) {
        v8s a = *(const v8s*)(lX + (w * 16 + m16) * 72 + kk + quad * 8);
#pragma unroll
        for (int b = 0; b < 4; ++b) {
            v8s bb = *(const v8s*)(lW + (b * 16 + m16) * 72 + kk + quad * 8);
            acc[b] = __builtin_amdgcn_mfma_f32_16x16x32_bf16(a, bb, acc[b], 0, 0, 0);
        }
    }
    __syncthreads();
    float* lC = (float*)lX;
#pragma unroll
    for (int b = 0; b < 4; ++b)
#pragma unroll
        for (int r = 0; r < 4; ++r) {
            int rowt = w * 16 + quad * 4 + r;
            lC[rowt * 65 + b * 16 + m16] = acc[b][r];
        }
    __syncthreads();
#pragma unroll
    for (int i = 0; i < 2; ++i) {
        int base = i * 2048 + tid * 8;
        int r = base >> 6;
        int c = base & 63;
        int gr = row0 + r;
        if (gr < n_nodes) {
            float d = dinv[gr];
            const float* p = lC + r * 65 + c;
            unsigned p0 = (unsigned)f2bf(p[0] * d) | ((unsigned)f2bf(p[1] * d) << 16);
            unsigned p1 = (unsigned)f2bf(p[2] * d) | ((unsigned)f2bf(p[3] * d) << 16);
            unsigned p2 = (unsigned)f2bf(p[4] * d) | ((unsigned)f2bf(p[5] * d) << 16);
            unsigned p3 = (unsigned)f2bf(p[6] * d) | ((unsigned)f2bf(p[7] * d) << 16);
            *(uint4*)(sout + (size_t)gr * 64 + c) = make_uint4(p0, p1, p2, p3);
        }
    }
}

// ---------------- layer2: group-per-node gather + Wfc dot + pool -----------
__launch_bounds__(256)
__global__ void k_layer2pool(const unsigned short* __restrict__ sin, const int* __restrict__ row_start,
                             const int* __restrict__ csr, const float* __restrict__ b2,
                             const float* __restrict__ dinv, const float* __restrict__ Wfc,
                             const int* __restrict__ batch,
                             float* gsum, int* gcnt, int n_nodes) {
    __shared__ float lsum[256];
    __shared__ int   lcnt[256];
    const int tid = threadIdx.x;
    lsum[tid] = 0.f; lcnt[tid] = 0;
    __syncthreads();
    const int lane = tid & 63;
    const int wave = tid >> 6;
    const int g = lane >> 4;
    const int l = lane & 15;
    const int n = (blockIdx.x * 4 + wave) * 4 + g;
    const bool valid = (n < n_nodes);
    const char* sp = (const char*)sin;
    const int SENTB = n_nodes << 7;

    int rs = 0, re = 0;
    if (valid) { rs = row_start[n]; re = row_start[n + 1]; }

    uint2 us = *(const uint2*)(sp + (size_t)(valid ? (n << 7) : SENTB) + l * 8);
    float4 acc;
    acc.x = bflo(us.x); acc.y = bfhi(us.x);
    acc.z = bflo(us.y); acc.w = bfhi(us.y);

    for (int base = rs; base < re; base += 16) {
        int p = base + l;
        int a = (p < re) ? csr[p] : SENTB;
#pragma unroll
        for (int j = 0; j < 16; ++j) {
            int ab = __shfl(a, g * 16 + j, 64);
            uint2 u = *(const uint2*)(sp + (size_t)(unsigned)ab + l * 8);
            acc.x += bflo(u.x); acc.y += bfhi(u.x);
            acc.z += bflo(u.y); acc.w += bfhi(u.y);
        }
    }
    float d = dinv[valid ? n : 0];
    const float4 b4  = ((const float4*)b2)[l];
    const float4 wf4 = ((const float4*)Wfc)[l];
    float t = fmaxf(fmaf(d, acc.x, b4.x), 0.f) * wf4.x
            + fmaxf(fmaf(d, acc.y, b4.y), 0.f) * wf4.y
            + fmaxf(fmaf(d, acc.z, b4.z), 0.f) * wf4.z
            + fmaxf(fmaf(d, acc.w, b4.w), 0.f) * wf4.w;
    // 16-lane tree within the group (shared shuffle instrs across 4 groups)
#pragma unroll
    for (int off = 8; off; off >>= 1) t += __shfl_down(t, off, 16);
    if (l == 0 && valid) {
        int gr = batch[n];
        atomicAdd(&lsum[gr], t);
        atomicAdd(&lcnt[gr], 1);
    }
    __syncthreads();
    if (lcnt[tid]) {
        atomicAdd(&gsum[tid], lsum[tid]);
        atomicAdd(&gcnt[tid], lcnt[tid]);
    }
}

__global__ void k_out(const float* __restrict__ gsum, const int* __restrict__ gcnt,
                      const float* __restrict__ bfc, float* out) {
    int g = threadIdx.x;
    if (g < 256) {
        float c = (float)(gcnt[g] > 1 ? gcnt[g] : 1);
        out[g] = gsum[g] / c + bfc[0];
    }
}

// ---------------------------------------------------------------------------
extern "C" void kernel_launch(void* const* d_in, const int* in_sizes, int n_in,
                              void* d_out, int out_size, void* d_ws, size_t ws_size,
                              hipStream_t stream) {
    const float* x   = (const float*)d_in[0];
    const int*   ei  = (const int*)d_in[1];
    const int*   bat = (const int*)d_in[2];
    const float* W1  = (const float*)d_in[3];
    const float* b1  = (const float*)d_in[4];
    const float* W2  = (const float*)d_in[5];
    const float* b2  = (const float*)d_in[6];
    const float* Wfc = (const float*)d_in[7];
    const float* bfc = (const float*)d_in[8];
    float* out = (float*)d_out;

    const int n_nodes = in_sizes[2];
    const int n_edges = in_sizes[1] / 2;
    const int* src = ei;
    const int* dst = ei + n_edges;
    const int NBUCK = (n_nodes + 127) >> 7;

    char* w = (char*)d_ws;
    size_t off = 0;
    auto alloc = [&](size_t bytes) -> void* {
        void* p = w + off;
        off += (bytes + 255) & ~(size_t)255;
        return p;
    };
    float* dinv = (float*)alloc((size_t)n_nodes * sizeof(float));
    unsigned short* bufA = (unsigned short*)alloc(((size_t)n_nodes + 1) * HIDDEN * 2);
    unsigned short* bufB = (unsigned short*)alloc(((size_t)n_nodes + 1) * HIDDEN * 2);
    float* tbuf = (float*)alloc((size_t)n_nodes * HIDDEN * sizeof(float));
    unsigned short* Wt   = (unsigned short*)alloc((size_t)HIDDEN * IN_DIM * 2);
    unsigned short* Wt2  = (unsigned short*)alloc((size_t)HIDDEN * HIDDEN * 2);
    float* gsum = (float*)alloc(256 * sizeof(float));
    int*   gcnt = (int*)  alloc(256 * sizeof(int));
    int*   cursor      = (int*)alloc((size_t)NB_MAX * sizeof(int));
    int*   bucket_base = (int*)alloc((size_t)NB_MAX * sizeof(int));
    unsigned* bucket_data = (unsigned*)alloc((size_t)NB_MAX * CAP * sizeof(unsigned));
    int* row_start = (int*)alloc(((size_t)n_nodes + 1) * sizeof(int));
    int* csr       = (int*)alloc(((size_t)n_edges + 64) * sizeof(int));
    (void)ws_size; (void)n_in; (void)out_size;

    hipLaunchKernelGGL(k_init, dim3(NB_MAX / 256), dim3(256), 0, stream,
                       cursor, gsum, gcnt, bufA, bufB, n_nodes);
    hipLaunchKernelGGL(k_bin, dim3((n_edges + 4095) / 4096), dim3(256), 0, stream,
                       src, dst, cursor, bucket_data, n_edges);
    hipLaunchKernelGGL(k_bexc, dim3(1), dim3(256), 0, stream,
                       cursor, bucket_base, row_start, n_nodes, NBUCK);
    hipLaunchKernelGGL(k_csr, dim3(NBUCK), dim3(256), 0, stream,
                       bucket_data, cursor, bucket_base, row_start, csr, dinv, n_nodes);
    hipLaunchKernelGGL(k_prep, dim3((HIDDEN * IN_DIM + HIDDEN * HIDDEN) / 256), dim3(256), 0, stream,
                       W1, W2, Wt, Wt2);
    hipLaunchKernelGGL(k_gemm1m, dim3((n_nodes + 63) / 64), dim3(256), 0, stream,
                       x, Wt, dinv, bufA, n_nodes);
    const int gb = (n_nodes + 15) / 16;   // 16 nodes per block (4 waves x 4 groups)
    hipLaunchKernelGGL(k_agg1, dim3(gb), dim3(256), 0, stream,
                       bufA, row_start, csr, dinv, tbuf, n_nodes);
    hipLaunchKernelGGL(k_gemm2m, dim3((n_nodes + 63) / 64), dim3(256), 0, stream,
                       tbuf, Wt2, b1, dinv, bufB, n_nodes);
    hipLaunchKernelGGL(k_layer2pool, dim3(gb), dim3(256), 0, stream,
                       bufB, row_start, csr, b2, dinv, Wfc, bat, gsum, gcnt, n_nodes);
    hipLaunchKernelGGL(k_out, dim3(1), dim3(256), 0, stream, gsum, gcnt, bfc, out);
}

// Round 7
// 422.353 us; speedup vs baseline: 1.3589x; 1.0311x over previous
//
#include <hip/hip_runtime.h>

#define HIDDEN 64
#define IN_DIM 512
#define CAP 4096      // bucket capacity (mean load ~2046 for E=1.6M over 782 buckets; 45 sigma headroom)
#define NB_MAX 1024   // max buckets (n_nodes <= 131072)

typedef short v8s __attribute__((ext_vector_type(8)));
typedef float v4f __attribute__((ext_vector_type(4)));

static __device__ __forceinline__ unsigned short f2bf(float f) {
    unsigned int u = __float_as_uint(f);
    u = (u + 0x7FFF + ((u >> 16) & 1)) >> 16;   // RNE
    return (unsigned short)u;
}
static __device__ __forceinline__ float bf2f(unsigned short u) {
    return __uint_as_float(((unsigned int)u) << 16);
}
static __device__ __forceinline__ float bflo(unsigned u) { return __uint_as_float(u << 16); }
static __device__ __forceinline__ float bfhi(unsigned u) { return __uint_as_float(u & 0xffff0000u); }

// ---------------- init: zero cursors + pool accumulators + sentinel rows ---
__global__ void k_init(int* cursor, float* gsum, int* gcnt,
                       unsigned short* bufA, unsigned short* bufB, int n_nodes) {
    int i = blockIdx.x * 256 + threadIdx.x;
    if (i < NB_MAX) cursor[i] = 0;
    if (i < 256) { gsum[i] = 0.f; gcnt[i] = 0; }
    if (i < 64) {
        bufA[(size_t)n_nodes * 64 + i] = 0;
        bufB[(size_t)n_nodes * 64 + i] = 0;
    }
}

// ---------------- bin edges by dst>>7 into fixed-stride buckets ------------
__launch_bounds__(256)
__global__ void k_bin(const int* __restrict__ src, const int* __restrict__ dst,
                      int* cursor, unsigned* __restrict__ bucket_data, int n_edges) {
    __shared__ unsigned words[4096];          // 16 KB
    __shared__ unsigned short binsh[4096];    // 8 KB
    __shared__ int hist[NB_MAX];              // 4 KB
    __shared__ int base[NB_MAX];              // 4 KB
    const int tid = threadIdx.x;
    const int e0 = blockIdx.x * 4096;
    for (int i = tid; i < NB_MAX; i += 256) hist[i] = 0;
    __syncthreads();
    for (int i = tid; i < 4096; i += 256) {
        int e = e0 + i;
        if (e < n_edges) {
            int d = dst[e], s = src[e];
            words[i] = ((unsigned)s << 7) | (unsigned)(d & 127);
            int b = d >> 7;
            binsh[i] = (unsigned short)b;
            atomicAdd(&hist[b], 1);
        } else binsh[i] = 0xFFFFu;
    }
    __syncthreads();
    for (int b = tid; b < NB_MAX; b += 256) {
        int c = hist[b];
        base[b] = c ? atomicAdd(&cursor[b], c) : 0;
        hist[b] = 0;
    }
    __syncthreads();
    for (int i = tid; i < 4096; i += 256) {
        unsigned short b = binsh[i];
        if (b != 0xFFFFu) {
            int slot = atomicAdd(&hist[b], 1);
            int p = base[b] + slot;
            if (p < CAP) bucket_data[(size_t)b * CAP + p] = words[i];
        }
    }
}

// ---------------- exclusive scan of bucket counts -> bucket_base -----------
__launch_bounds__(256)
__global__ void k_bexc(const int* __restrict__ cursor, int* __restrict__ bucket_base,
                       int* __restrict__ row_start, int n_nodes, int nbuck) {
    __shared__ int wsum[4];
    const int t = threadIdx.x, lane = t & 63, w = t >> 6;
    int v[4], s = 0;
#pragma unroll
    for (int k = 0; k < 4; ++k) {
        int i = t * 4 + k;
        int c = (i < nbuck) ? cursor[i] : 0;
        if (c > CAP) c = CAP;
        v[k] = s; s += c;
    }
    int inc = s;
#pragma unroll
    for (int off = 1; off < 64; off <<= 1) {
        int u = __shfl_up(inc, off, 64);
        if (lane >= off) inc += u;
    }
    if (lane == 63) wsum[w] = inc;
    __syncthreads();
    int cross = 0;
    for (int i = 0; i < w; ++i) cross += wsum[i];
    int b0 = cross + inc - s;
#pragma unroll
    for (int k = 0; k < 4; ++k) {
        int i = t * 4 + k;
        if (i < NB_MAX) bucket_base[i] = b0 + v[k];
    }
    if (t == 255) row_start[n_nodes] = cross + inc;   // total kept edges
}

// ---------------- per-bucket CSR build (coalesced, local LDS) --------------
// csr entries are PRE-SCALED byte offsets (src*128) for the gather kernels.
__launch_bounds__(256)
__global__ void k_csr(const unsigned* __restrict__ bucket_data, const int* __restrict__ cursor,
                      const int* __restrict__ bucket_base,
                      int* __restrict__ row_start, int* __restrict__ csr,
                      float* __restrict__ dinv, int n_nodes) {
    __shared__ unsigned words[CAP];   // 16 KB
    __shared__ int cnt[128];
    __shared__ int loff[128];
    __shared__ int cur[128];
    __shared__ int w0sum;
    const int tid = threadIdx.x, bin = blockIdx.x, n0 = bin << 7;
    int c = cursor[bin]; if (c > CAP) c = CAP;
    const unsigned* bd = bucket_data + (size_t)bin * CAP;
    for (int i = tid; i < c; i += 256) words[i] = bd[i];
    if (tid < 128) { cnt[tid] = 0; cur[tid] = 0; }
    __syncthreads();
    for (int i = tid; i < c; i += 256) atomicAdd(&cnt[words[i] & 127], 1);
    __syncthreads();
    int val = 0, inc = 0;
    if (tid < 128) {
        const int lane = tid & 63;
        val = cnt[tid];
        inc = val;
#pragma unroll
        for (int off = 1; off < 64; off <<= 1) {
            int u = __shfl_up(inc, off, 64);
            if (lane >= off) inc += u;
        }
        if (tid == 63) w0sum = inc;
    }
    __syncthreads();
    if (tid < 128) {
        int excl = inc - val + ((tid >= 64) ? w0sum : 0);
        loff[tid] = excl;
        int n = n0 + tid;
        if (n < n_nodes) {
            row_start[n] = bucket_base[bin] + excl;
            dinv[n] = rsqrtf((float)(val + 1));   // +1 self loop
        }
    }
    __syncthreads();
    const int gbase = bucket_base[bin];
    for (int i = tid; i < c; i += 256) {
        unsigned wd = words[i];
        int d = wd & 127;
        int slot = atomicAdd(&cur[d], 1);
        csr[gbase + loff[d] + slot] = (int)(wd & 0xFFFFFF80u);  // src*128 byte offset
    }
}

// ---------------- W1,W2 -> bf16 transposed Wt [64][512], Wt2 [64][64] ------
__global__ void k_prep(const float* __restrict__ W1, const float* __restrict__ W2,
                       unsigned short* __restrict__ Wt, unsigned short* __restrict__ Wt2) {
    int idx = blockIdx.x * 256 + threadIdx.x;
    if (idx < HIDDEN * IN_DIM) {
        int n = idx >> 9, k = idx & 511;
        Wt[(size_t)n * 512 + k] = f2bf(W1[(size_t)k * 64 + n]);
    } else {
        int j = idx - HIDDEN * IN_DIM;   // 0..4095
        int n = j >> 6, k = j & 63;
        Wt2[(size_t)n * 64 + k] = f2bf(W2[(size_t)k * 64 + n]);
    }
}

// ---------------- GEMM1 (MFMA bf16): s1 = bf16(dinv .* (x @ W1)) -----------
__launch_bounds__(256)
__global__ void k_gemm1m(const float* __restrict__ x, const unsigned short* __restrict__ Wt,
                         const float* __restrict__ dinv, unsigned short* __restrict__ s1,
                         int n_nodes) {
    __shared__ __align__(16) unsigned short lX[64 * 136];
    __shared__ __align__(16) unsigned short lW[64 * 136];
    const int tid  = threadIdx.x;
    const int lane = tid & 63;
    const int w    = tid >> 6;
    const int quad = lane >> 4;
    const int m16  = lane & 15;
    const int row0 = blockIdx.x * 64;

    v4f acc[4];
#pragma unroll
    for (int b = 0; b < 4; ++b) acc[b] = (v4f){0.f, 0.f, 0.f, 0.f};

    for (int kc = 0; kc < IN_DIM; kc += 128) {
        __syncthreads();
#pragma unroll
        for (int i = 0; i < 8; ++i) {
            int fidx = tid + i * 256;
            int r  = fidx >> 5;
            int c4 = fidx & 31;
            int gr = row0 + r;
            float4 v = make_float4(0.f, 0.f, 0.f, 0.f);
            if (gr < n_nodes) v = ((const float4*)(x + (size_t)gr * IN_DIM + kc))[c4];
            ushort4 u = make_ushort4(f2bf(v.x), f2bf(v.y), f2bf(v.z), f2bf(v.w));
            *(ushort4*)(lX + r * 136 + c4 * 4) = u;
        }
#pragma unroll
        for (int i = 0; i < 4; ++i) {
            int idx = tid + i * 256;
            int n  = idx >> 4;
            int c8 = idx & 15;
            uint4 u = *(const uint4*)(Wt + (size_t)n * 512 + kc + c8 * 8);
            *(uint4*)(lW + n * 136 + c8 * 8) = u;
        }
        __syncthreads();
#pragma unroll
        for (int kk = 0; kk < 128; kk += 32) {
            v8s a = *(const v8s*)(lX + (w * 16 + m16) * 136 + kk + quad * 8);
#pragma unroll
            for (int b = 0; b < 4; ++b) {
                v8s bb = *(const v8s*)(lW + (b * 16 + m16) * 136 + kk + quad * 8);
                acc[b] = __builtin_amdgcn_mfma_f32_16x16x32_bf16(a, bb, acc[b], 0, 0, 0);
            }
        }
    }
    __syncthreads();
    float* lC = (float*)lX;
#pragma unroll
    for (int b = 0; b < 4; ++b)
#pragma unroll
        for (int r = 0; r < 4; ++r) {
            int rowt = w * 16 + quad * 4 + r;
            lC[rowt * 65 + b * 16 + m16] = acc[b][r];
        }
    __syncthreads();
#pragma unroll
    for (int i = 0; i < 2; ++i) {
        int base = i * 2048 + tid * 8;
        int r = base >> 6;
        int c = base & 63;
        int gr = row0 + r;
        if (gr < n_nodes) {
            float d = dinv[gr];
            const float* p = lC + r * 65 + c;
            unsigned p0 = (unsigned)f2bf(p[0] * d) | ((unsigned)f2bf(p[1] * d) << 16);
            unsigned p1 = (unsigned)f2bf(p[2] * d) | ((unsigned)f2bf(p[3] * d) << 16);
            unsigned p2 = (unsigned)f2bf(p[4] * d) | ((unsigned)f2bf(p[5] * d) << 16);
            unsigned p3 = (unsigned)f2bf(p[6] * d) | ((unsigned)f2bf(p[7] * d) << 16);
            *(uint4*)(s1 + (size_t)gr * 64 + c) = make_uint4(p0, p1, p2, p3);
        }
    }
}

// ---------------- agg1: 8-lane-group gather, t = dinv.*(sum nbrs + self) ---
// 8-lane group owns one node: lane l holds features 8l..8l+7 (16 B) -> one
// dwordx4 per row serves 8 edges per wave-instruction (1 KB/instr). Two
// dword csr loads per 16-edge chunk keep 16 gathers in flight. No cross-lane
// reduce. Guard-free: sentinel zero row for padded slots.
__launch_bounds__(256)
__global__ void k_agg1(const unsigned short* __restrict__ sin, const int* __restrict__ row_start,
                       const int* __restrict__ csr, const float* __restrict__ dinv,
                       float* __restrict__ tout, int n_nodes) {
    const int tid  = threadIdx.x;
    const int lane = tid & 63;
    const int wave = tid >> 6;
    const int g = lane >> 3;     // node slot within wave (0..7)
    const int l = lane & 7;      // feature lane: floats 8l..8l+7
    const int n = (blockIdx.x * 4 + wave) * 8 + g;
    const bool valid = (n < n_nodes);
    const char* sp = (const char*)sin;
    const int SENTB = n_nodes << 7;   // sentinel zero row (byte offset)

    int rs = 0, re = 0;
    if (valid) { rs = row_start[n]; re = row_start[n + 1]; }

    // init acc with the self row (sentinel for invalid slots)
    uint4 us = *(const uint4*)(sp + (size_t)(valid ? (n << 7) : SENTB) + l * 16);
    float acc0 = bflo(us.x), acc1 = bfhi(us.x);
    float acc2 = bflo(us.y), acc3 = bfhi(us.y);
    float acc4 = bflo(us.z), acc5 = bfhi(us.z);
    float acc6 = bflo(us.w), acc7 = bfhi(us.w);

    for (int base = rs; base < re; base += 16) {
        int p0 = base + l;        // l in 0..7
        int p1 = base + 8 + l;
        int a0 = (p0 < re) ? csr[p0] : SENTB;
        int a1 = (p1 < re) ? csr[p1] : SENTB;
#pragma unroll
        for (int j = 0; j < 8; ++j) {
            int ab = __shfl(a0, g * 8 + j, 64);
            uint4 u = *(const uint4*)(sp + (size_t)(unsigned)ab + l * 16);
            acc0 += bflo(u.x); acc1 += bfhi(u.x);
            acc2 += bflo(u.y); acc3 += bfhi(u.y);
            acc4 += bflo(u.z); acc5 += bfhi(u.z);
            acc6 += bflo(u.w); acc7 += bfhi(u.w);
        }
#pragma unroll
        for (int j = 0; j < 8; ++j) {
            int ab = __shfl(a1, g * 8 + j, 64);
            uint4 u = *(const uint4*)(sp + (size_t)(unsigned)ab + l * 16);
            acc0 += bflo(u.x); acc1 += bfhi(u.x);
            acc2 += bflo(u.y); acc3 += bfhi(u.y);
            acc4 += bflo(u.z); acc5 += bfhi(u.z);
            acc6 += bflo(u.w); acc7 += bfhi(u.w);
        }
    }
    if (valid) {
        float d = dinv[n];
        float* op = tout + (size_t)n * HIDDEN + l * 8;
        *(float4*)op       = make_float4(d * acc0, d * acc1, d * acc2, d * acc3);
        *(float4*)(op + 4) = make_float4(d * acc4, d * acc5, d * acc6, d * acc7);
    }
}

// ---------------- GEMM2 (MFMA bf16): bufB = bf16(dinv .* (relu(t+b1)@W2)) --
__launch_bounds__(256)
__global__ void k_gemm2m(const float* __restrict__ tin, const unsigned short* __restrict__ Wt2,
                         const float* __restrict__ b1, const float* __restrict__ dinv,
                         unsigned short* __restrict__ sout, int n_nodes) {
    __shared__ __align__(16) unsigned short lX[64 * 136];  // staging stride 72; f32 stride-65 epilogue overlay
    __shared__ __align__(16) unsigned short lW[64 * 72];
    const int tid  = threadIdx.x;
    const int lane = tid & 63;
    const int w    = tid >> 6;
    const int quad = lane >> 4;
    const int m16  = lane & 15;
    const int row0 = blockIdx.x * 64;

    // stage A = bf16(relu(t + b1)), 64x64
#pragma unroll
    for (int i = 0; i < 4; ++i) {
        int fidx = tid + i * 256;   // 0..1023
        int r  = fidx >> 4;
        int c4 = fidx & 15;
        int gr = row0 + r;
        float4 v = make_float4(0.f, 0.f, 0.f, 0.f);
        if (gr < n_nodes) v = ((const float4*)(tin + (size_t)gr * HIDDEN))[c4];
        float4 bb = ((const float4*)b1)[c4];
        v.x = fmaxf(v.x + bb.x, 0.f);
        v.y = fmaxf(v.y + bb.y, 0.f);
        v.z = fmaxf(v.z + bb.z, 0.f);
        v.w = fmaxf(v.w + bb.w, 0.f);
        ushort4 u = make_ushort4(f2bf(v.x), f2bf(v.y), f2bf(v.z), f2bf(v.w));
        *(ushort4*)(lX + r * 72 + c4 * 4) = u;
    }
    // stage W2^T bf16, 64x64
#pragma unroll
    for (int i = 0; i < 2; ++i) {
        int idx = tid + i * 256;   // 0..511
        int n  = idx >> 3;
        int c8 = idx & 7;
        uint4 u = *(const uint4*)(Wt2 + (size_t)n * 64 + c8 * 8);
        *(uint4*)(lW + n * 72 + c8 * 8) = u;
    }
    __syncthreads();
    v4f acc[4];
#pragma unroll
    for (int b = 0; b < 4; ++b) acc[b] = (v4f){0.f, 0.f, 0.f, 0.f};
#pragma unroll
    for (int kk = 0; kk < 64; kk += 32) {
        v8s a = *(const v8s*)(lX + (w * 16 + m16) * 72 + kk + quad * 8);
#pragma unroll
        for (int b = 0; b < 4; ++b) {
            v8s bb = *(const v8s*)(lW + (b * 16 + m16) * 72 + kk + quad * 8);
            acc[b] = __builtin_amdgcn_mfma_f32_16x16x32_bf16(a, bb, acc[b], 0, 0, 0);
        }
    }
    __syncthreads();
    float* lC = (float*)lX;
#pragma unroll
    for (int b = 0; b < 4; ++b)
#pragma unroll
        for (int r = 0; r < 4; ++r) {
            int rowt = w * 16 + quad * 4 + r;
            lC[rowt * 65 + b * 16 + m16] = acc[b][r];
        }
    __syncthreads();
#pragma unroll
    for (int i = 0; i < 2; ++i) {
        int base = i * 2048 + tid * 8;
        int r = base >> 6;
        int c = base & 63;
        int gr = row0 + r;
        if (gr < n_nodes) {
            float d = dinv[gr];
            const float* p = lC + r * 65 + c;
            unsigned p0 = (unsigned)f2bf(p[0] * d) | ((unsigned)f2bf(p[1] * d) << 16);
            unsigned p1 = (unsigned)f2bf(p[2] * d) | ((unsigned)f2bf(p[3] * d) << 16);
            unsigned p2 = (unsigned)f2bf(p[4] * d) | ((unsigned)f2bf(p[5] * d) << 16);
            unsigned p3 = (unsigned)f2bf(p[6] * d) | ((unsigned)f2bf(p[7] * d) << 16);
            *(uint4*)(sout + (size_t)gr * 64 + c) = make_uint4(p0, p1, p2, p3);
        }
    }
}

// ---------------- layer2: 8-lane-group gather + Wfc dot + pool -------------
__launch_bounds__(256)
__global__ void k_layer2pool(const unsigned short* __restrict__ sin, const int* __restrict__ row_start,
                             const int* __restrict__ csr, const float* __restrict__ b2,
                             const float* __restrict__ dinv, const float* __restrict__ Wfc,
                             const int* __restrict__ batch,
                             float* gsum, int* gcnt, int n_nodes) {
    __shared__ float lsum[256];
    __shared__ int   lcnt[256];
    const int tid = threadIdx.x;
    lsum[tid] = 0.f; lcnt[tid] = 0;
    __syncthreads();
    const int lane = tid & 63;
    const int wave = tid >> 6;
    const int g = lane >> 3;
    const int l = lane & 7;
    const int n = (blockIdx.x * 4 + wave) * 8 + g;
    const bool valid = (n < n_nodes);
    const char* sp = (const char*)sin;
    const int SENTB = n_nodes << 7;

    int rs = 0, re = 0;
    if (valid) { rs = row_start[n]; re = row_start[n + 1]; }

    uint4 us = *(const uint4*)(sp + (size_t)(valid ? (n << 7) : SENTB) + l * 16);
    float acc0 = bflo(us.x), acc1 = bfhi(us.x);
    float acc2 = bflo(us.y), acc3 = bfhi(us.y);
    float acc4 = bflo(us.z), acc5 = bfhi(us.z);
    float acc6 = bflo(us.w), acc7 = bfhi(us.w);

    for (int base = rs; base < re; base += 16) {
        int p0 = base + l;
        int p1 = base + 8 + l;
        int a0 = (p0 < re) ? csr[p0] : SENTB;
        int a1 = (p1 < re) ? csr[p1] : SENTB;
#pragma unroll
        for (int j = 0; j < 8; ++j) {
            int ab = __shfl(a0, g * 8 + j, 64);
            uint4 u = *(const uint4*)(sp + (size_t)(unsigned)ab + l * 16);
            acc0 += bflo(u.x); acc1 += bfhi(u.x);
            acc2 += bflo(u.y); acc3 += bfhi(u.y);
            acc4 += bflo(u.z); acc5 += bfhi(u.z);
            acc6 += bflo(u.w); acc7 += bfhi(u.w);
        }
#pragma unroll
        for (int j = 0; j < 8; ++j) {
            int ab = __shfl(a1, g * 8 + j, 64);
            uint4 u = *(const uint4*)(sp + (size_t)(unsigned)ab + l * 16);
            acc0 += bflo(u.x); acc1 += bfhi(u.x);
            acc2 += bflo(u.y); acc3 += bfhi(u.y);
            acc4 += bflo(u.z); acc5 += bfhi(u.z);
            acc6 += bflo(u.w); acc7 += bfhi(u.w);
        }
    }
    float d = dinv[valid ? n : 0];
    const float4 bA  = ((const float4*)b2)[2 * l];
    const float4 bB  = ((const float4*)b2)[2 * l + 1];
    const float4 wA  = ((const float4*)Wfc)[2 * l];
    const float4 wB  = ((const float4*)Wfc)[2 * l + 1];
    float t = fmaxf(fmaf(d, acc0, bA.x), 0.f) * wA.x
            + fmaxf(fmaf(d, acc1, bA.y), 0.f) * wA.y
            + fmaxf(fmaf(d, acc2, bA.z), 0.f) * wA.z
            + fmaxf(fmaf(d, acc3, bA.w), 0.f) * wA.w
            + fmaxf(fmaf(d, acc4, bB.x), 0.f) * wB.x
            + fmaxf(fmaf(d, acc5, bB.y), 0.f) * wB.y
            + fmaxf(fmaf(d, acc6, bB.z), 0.f) * wB.z
            + fmaxf(fmaf(d, acc7, bB.w), 0.f) * wB.w;
    // 8-lane tree within the group (shared shuffle instrs across 8 groups)
#pragma unroll
    for (int off = 4; off; off >>= 1) t += __shfl_down(t, off, 8);
    if (l == 0 && valid) {
        int gr = batch[n];
        atomicAdd(&lsum[gr], t);
        atomicAdd(&lcnt[gr], 1);
    }
    __syncthreads();
    if (lcnt[tid]) {
        atomicAdd(&gsum[tid], lsum[tid]);
        atomicAdd(&gcnt[tid], lcnt[tid]);
    }
}

__global__ void k_out(const float* __restrict__ gsum, const int* __restrict__ gcnt,
                      const float* __restrict__ bfc, float* out) {
    int g = threadIdx.x;
    if (g < 256) {
        float c = (float)(gcnt[g] > 1 ? gcnt[g] : 1);
        out[g] = gsum[g] / c + bfc[0];
    }
}

// ---------------------------------------------------------------------------
extern "C" void kernel_launch(void* const* d_in, const int* in_sizes, int n_in,
                              void* d_out, int out_size, void* d_ws, size_t ws_size,
                              hipStream_t stream) {
    const float* x   = (const float*)d_in[0];
    const int*   ei  = (const int*)d_in[1];
    const int*   bat = (const int*)d_in[2];
    const float* W1  = (const float*)d_in[3];
    const float* b1  = (const float*)d_in[4];
    const float* W2  = (const float*)d_in[5];
    const float* b2  = (const float*)d_in[6];
    const float* Wfc = (const float*)d_in[7];
    const float* bfc = (const float*)d_in[8];
    float* out = (float*)d_out;

    const int n_nodes = in_sizes[2];
    const int n_edges = in_sizes[1] / 2;
    const int* src = ei;
    const int* dst = ei + n_edges;
    const int NBUCK = (n_nodes + 127) >> 7;

    char* w = (char*)d_ws;
    size_t off = 0;
    auto alloc = [&](size_t bytes) -> void* {
        void* p = w + off;
        off += (bytes + 255) & ~(size_t)255;
        return p;
    };
    float* dinv = (float*)alloc((size_t)n_nodes * sizeof(float));
    unsigned short* bufA = (unsigned short*)alloc(((size_t)n_nodes + 1) * HIDDEN * 2);
    unsigned short* bufB = (unsigned short*)alloc(((size_t)n_nodes + 1) * HIDDEN * 2);
    float* tbuf = (float*)alloc((size_t)n_nodes * HIDDEN * sizeof(float));
    unsigned short* Wt   = (unsigned short*)alloc((size_t)HIDDEN * IN_DIM * 2);
    unsigned short* Wt2  = (unsigned short*)alloc((size_t)HIDDEN * HIDDEN * 2);
    float* gsum = (float*)alloc(256 * sizeof(float));
    int*   gcnt = (int*)  alloc(256 * sizeof(int));
    int*   cursor      = (int*)alloc((size_t)NB_MAX * sizeof(int));
    int*   bucket_base = (int*)alloc((size_t)NB_MAX * sizeof(int));
    unsigned* bucket_data = (unsigned*)alloc((size_t)NB_MAX * CAP * sizeof(unsigned));
    int* row_start = (int*)alloc(((size_t)n_nodes + 1) * sizeof(int));
    int* csr       = (int*)alloc(((size_t)n_edges + 64) * sizeof(int));
    (void)ws_size; (void)n_in; (void)out_size;

    hipLaunchKernelGGL(k_init, dim3(NB_MAX / 256), dim3(256), 0, stream,
                       cursor, gsum, gcnt, bufA, bufB, n_nodes);
    hipLaunchKernelGGL(k_bin, dim3((n_edges + 4095) / 4096), dim3(256), 0, stream,
                       src, dst, cursor, bucket_data, n_edges);
    hipLaunchKernelGGL(k_bexc, dim3(1), dim3(256), 0, stream,
                       cursor, bucket_base, row_start, n_nodes, NBUCK);
    hipLaunchKernelGGL(k_csr, dim3(NBUCK), dim3(256), 0, stream,
                       bucket_data, cursor, bucket_base, row_start, csr, dinv, n_nodes);
    hipLaunchKernelGGL(k_prep, dim3((HIDDEN * IN_DIM + HIDDEN * HIDDEN) / 256), dim3(256), 0, stream,
                       W1, W2, Wt, Wt2);
    hipLaunchKernelGGL(k_gemm1m, dim3((n_nodes + 63) / 64), dim3(256), 0, stream,
                       x, Wt, dinv, bufA, n_nodes);
    const int gb = (n_nodes + 31) / 32;   // 32 nodes per block (4 waves x 8 groups)
    hipLaunchKernelGGL(k_agg1, dim3(gb), dim3(256), 0, stream,
                       bufA, row_start, csr, dinv, tbuf, n_nodes);
    hipLaunchKernelGGL(k_gemm2m, dim3((n_nodes + 63) / 64), dim3(256), 0, stream,
                       tbuf, Wt2, b1, dinv, bufB, n_nodes);
    hipLaunchKernelGGL(k_layer2pool, dim3(gb), dim3(256), 0, stream,
                       bufB, row_start, csr, b2, dinv, Wfc, bat, gsum, gcnt, n_nodes);
    hipLaunchKernelGGL(k_out, dim3(1), dim3(256), 0, stream, gsum, gcnt, bfc, out);
}

// Round 8
// 415.282 us; speedup vs baseline: 1.3821x; 1.0170x over previous
//
#include <hip/hip_runtime.h>

#define HIDDEN 64
#define IN_DIM 512
#define CAP 4096      // bucket capacity (mean load ~2046 for E=1.6M over 782 buckets; 45 sigma headroom)
#define NB_MAX 1024   // max buckets (n_nodes <= 131072)

typedef short v8s __attribute__((ext_vector_type(8)));
typedef float v4f __attribute__((ext_vector_type(4)));

static __device__ __forceinline__ unsigned short f2bf(float f) {
    unsigned int u = __float_as_uint(f);
    u = (u + 0x7FFF + ((u >> 16) & 1)) >> 16;   // RNE
    return (unsigned short)u;
}
static __device__ __forceinline__ float bf2f(unsigned short u) {
    return __uint_as_float(((unsigned int)u) << 16);
}
static __device__ __forceinline__ float bflo(unsigned u) { return __uint_as_float(u << 16); }
static __device__ __forceinline__ float bfhi(unsigned u) { return __uint_as_float(u & 0xffff0000u); }

// ---------------- init: zero cursors + pool accumulators + sentinel rows ---
__global__ void k_init(int* cursor, float* gsum, int* gcnt,
                       unsigned short* bufA, unsigned short* bufB, int n_nodes) {
    int i = blockIdx.x * 256 + threadIdx.x;
    if (i < NB_MAX) cursor[i] = 0;
    if (i < 256) { gsum[i] = 0.f; gcnt[i] = 0; }
    if (i < 64) {
        bufA[(size_t)n_nodes * 64 + i] = 0;
        bufB[(size_t)n_nodes * 64 + i] = 0;
    }
}

// ---------------- bin edges by dst>>7 into fixed-stride buckets ------------
__launch_bounds__(256)
__global__ void k_bin(const int* __restrict__ src, const int* __restrict__ dst,
                      int* cursor, unsigned* __restrict__ bucket_data, int n_edges) {
    __shared__ unsigned words[4096];          // 16 KB
    __shared__ unsigned short binsh[4096];    // 8 KB
    __shared__ int hist[NB_MAX];              // 4 KB
    __shared__ int base[NB_MAX];              // 4 KB
    const int tid = threadIdx.x;
    const int e0 = blockIdx.x * 4096;
    for (int i = tid; i < NB_MAX; i += 256) hist[i] = 0;
    __syncthreads();
    for (int i = tid; i < 4096; i += 256) {
        int e = e0 + i;
        if (e < n_edges) {
            int d = dst[e], s = src[e];
            words[i] = ((unsigned)s << 7) | (unsigned)(d & 127);
            int b = d >> 7;
            binsh[i] = (unsigned short)b;
            atomicAdd(&hist[b], 1);
        } else binsh[i] = 0xFFFFu;
    }
    __syncthreads();
    for (int b = tid; b < NB_MAX; b += 256) {
        int c = hist[b];
        base[b] = c ? atomicAdd(&cursor[b], c) : 0;
        hist[b] = 0;
    }
    __syncthreads();
    for (int i = tid; i < 4096; i += 256) {
        unsigned short b = binsh[i];
        if (b != 0xFFFFu) {
            int slot = atomicAdd(&hist[b], 1);
            int p = base[b] + slot;
            if (p < CAP) bucket_data[(size_t)b * CAP + p] = words[i];
        }
    }
}

// ---------------- exclusive scan of bucket counts -> bucket_base -----------
__launch_bounds__(256)
__global__ void k_bexc(const int* __restrict__ cursor, int* __restrict__ bucket_base,
                       int* __restrict__ row_start, int n_nodes, int nbuck) {
    __shared__ int wsum[4];
    const int t = threadIdx.x, lane = t & 63, w = t >> 6;
    int v[4], s = 0;
#pragma unroll
    for (int k = 0; k < 4; ++k) {
        int i = t * 4 + k;
        int c = (i < nbuck) ? cursor[i] : 0;
        if (c > CAP) c = CAP;
        v[k] = s; s += c;
    }
    int inc = s;
#pragma unroll
    for (int off = 1; off < 64; off <<= 1) {
        int u = __shfl_up(inc, off, 64);
        if (lane >= off) inc += u;
    }
    if (lane == 63) wsum[w] = inc;
    __syncthreads();
    int cross = 0;
    for (int i = 0; i < w; ++i) cross += wsum[i];
    int b0 = cross + inc - s;
#pragma unroll
    for (int k = 0; k < 4; ++k) {
        int i = t * 4 + k;
        if (i < NB_MAX) bucket_base[i] = b0 + v[k];
    }
    if (t == 255) row_start[n_nodes] = cross + inc;   // total kept edges
}

// ---------------- per-bucket CSR build (coalesced, local LDS) --------------
// csr entries are PRE-SCALED byte offsets (src*128) for the gather kernels.
__launch_bounds__(256)
__global__ void k_csr(const unsigned* __restrict__ bucket_data, const int* __restrict__ cursor,
                      const int* __restrict__ bucket_base,
                      int* __restrict__ row_start, int* __restrict__ csr,
                      float* __restrict__ dinv, int n_nodes) {
    __shared__ unsigned words[CAP];   // 16 KB
    __shared__ int cnt[128];
    __shared__ int loff[128];
    __shared__ int cur[128];
    __shared__ int w0sum;
    const int tid = threadIdx.x, bin = blockIdx.x, n0 = bin << 7;
    int c = cursor[bin]; if (c > CAP) c = CAP;
    const unsigned* bd = bucket_data + (size_t)bin * CAP;
    for (int i = tid; i < c; i += 256) words[i] = bd[i];
    if (tid < 128) { cnt[tid] = 0; cur[tid] = 0; }
    __syncthreads();
    for (int i = tid; i < c; i += 256) atomicAdd(&cnt[words[i] & 127], 1);
    __syncthreads();
    int val = 0, inc = 0;
    if (tid < 128) {
        const int lane = tid & 63;
        val = cnt[tid];
        inc = val;
#pragma unroll
        for (int off = 1; off < 64; off <<= 1) {
            int u = __shfl_up(inc, off, 64);
            if (lane >= off) inc += u;
        }
        if (tid == 63) w0sum = inc;
    }
    __syncthreads();
    if (tid < 128) {
        int excl = inc - val + ((tid >= 64) ? w0sum : 0);
        loff[tid] = excl;
        int n = n0 + tid;
        if (n < n_nodes) {
            row_start[n] = bucket_base[bin] + excl;
            dinv[n] = rsqrtf((float)(val + 1));   // +1 self loop
        }
    }
    __syncthreads();
    const int gbase = bucket_base[bin];
    for (int i = tid; i < c; i += 256) {
        unsigned wd = words[i];
        int d = wd & 127;
        int slot = atomicAdd(&cur[d], 1);
        csr[gbase + loff[d] + slot] = (int)(wd & 0xFFFFFF80u);  // src*128 byte offset
    }
}

// ---------------- W1,W2 -> bf16 transposed Wt [64][512], Wt2 [64][64] ------
__global__ void k_prep(const float* __restrict__ W1, const float* __restrict__ W2,
                       unsigned short* __restrict__ Wt, unsigned short* __restrict__ Wt2) {
    int idx = blockIdx.x * 256 + threadIdx.x;
    if (idx < HIDDEN * IN_DIM) {
        int n = idx >> 9, k = idx & 511;
        Wt[(size_t)n * 512 + k] = f2bf(W1[(size_t)k * 64 + n]);
    } else {
        int j = idx - HIDDEN * IN_DIM;   // 0..4095
        int n = j >> 6, k = j & 63;
        Wt2[(size_t)n * 64 + k] = f2bf(W2[(size_t)k * 64 + n]);
    }
}

// ---------------- GEMM1 (MFMA bf16): s1 = bf16(dinv .* (x @ W1)) -----------
__launch_bounds__(256)
__global__ void k_gemm1m(const float* __restrict__ x, const unsigned short* __restrict__ Wt,
                         const float* __restrict__ dinv, unsigned short* __restrict__ s1,
                         int n_nodes) {
    __shared__ __align__(16) unsigned short lX[64 * 136];
    __shared__ __align__(16) unsigned short lW[64 * 136];
    const int tid  = threadIdx.x;
    const int lane = tid & 63;
    const int w    = tid >> 6;
    const int quad = lane >> 4;
    const int m16  = lane & 15;
    const int row0 = blockIdx.x * 64;

    v4f acc[4];
#pragma unroll
    for (int b = 0; b < 4; ++b) acc[b] = (v4f){0.f, 0.f, 0.f, 0.f};

    for (int kc = 0; kc < IN_DIM; kc += 128) {
        __syncthreads();
#pragma unroll
        for (int i = 0; i < 8; ++i) {
            int fidx = tid + i * 256;
            int r  = fidx >> 5;
            int c4 = fidx & 31;
            int gr = row0 + r;
            float4 v = make_float4(0.f, 0.f, 0.f, 0.f);
            if (gr < n_nodes) v = ((const float4*)(x + (size_t)gr * IN_DIM + kc))[c4];
            ushort4 u = make_ushort4(f2bf(v.x), f2bf(v.y), f2bf(v.z), f2bf(v.w));
            *(ushort4*)(lX + r * 136 + c4 * 4) = u;
        }
#pragma unroll
        for (int i = 0; i < 4; ++i) {
            int idx = tid + i * 256;
            int n  = idx >> 4;
            int c8 = idx & 15;
            uint4 u = *(const uint4*)(Wt + (size_t)n * 512 + kc + c8 * 8);
            *(uint4*)(lW + n * 136 + c8 * 8) = u;
        }
        __syncthreads();
#pragma unroll
        for (int kk = 0; kk < 128; kk += 32) {
            v8s a = *(const v8s*)(lX + (w * 16 + m16) * 136 + kk + quad * 8);
#pragma unroll
            for (int b = 0; b < 4; ++b) {
                v8s bb = *(const v8s*)(lW + (b * 16 + m16) * 136 + kk + quad * 8);
                acc[b] = __builtin_amdgcn_mfma_f32_16x16x32_bf16(a, bb, acc[b], 0, 0, 0);
            }
        }
    }
    __syncthreads();
    float* lC = (float*)lX;
#pragma unroll
    for (int b = 0; b < 4; ++b)
#pragma unroll
        for (int r = 0; r < 4; ++r) {
            int rowt = w * 16 + quad * 4 + r;
            lC[rowt * 65 + b * 16 + m16] = acc[b][r];
        }
    __syncthreads();
#pragma unroll
    for (int i = 0; i < 2; ++i) {
        int base = i * 2048 + tid * 8;
        int r = base >> 6;
        int c = base & 63;
        int gr = row0 + r;
        if (gr < n_nodes) {
            float d = dinv[gr];
            const float* p = lC + r * 65 + c;
            unsigned p0 = (unsigned)f2bf(p[0] * d) | ((unsigned)f2bf(p[1] * d) << 16);
            unsigned p1 = (unsigned)f2bf(p[2] * d) | ((unsigned)f2bf(p[3] * d) << 16);
            unsigned p2 = (unsigned)f2bf(p[4] * d) | ((unsigned)f2bf(p[5] * d) << 16);
            unsigned p3 = (unsigned)f2bf(p[6] * d) | ((unsigned)f2bf(p[7] * d) << 16);
            *(uint4*)(s1 + (size_t)gr * 64 + c) = make_uint4(p0, p1, p2, p3);
        }
    }
}

// ---------------- fused layer1: 8-lane-group gather + block MFMA GEMM2 -----
// Gather phase identical to round 7 (8-lane group per node, dwordx4 = 1 KB
// per wave-instruction). Then the block's 32 gathered nodes form the A-tile
// of a 32x64x64 MFMA GEMM against staged W2^T: one bf16 LDS write per lane,
// 2 barriers, 4 MFMAs/wave, LDS-transpose epilogue. Kills the tbuf round
// trip (51 MB) and one dispatch vs the split version.
__launch_bounds__(256)
__global__ void k_agg1g2(const unsigned short* __restrict__ sin, const int* __restrict__ row_start,
                         const int* __restrict__ csr, const float* __restrict__ dinv,
                         const unsigned short* __restrict__ Wt2, const float* __restrict__ b1,
                         unsigned short* __restrict__ sout, int n_nodes) {
    __shared__ __align__(16) unsigned short lW[64 * 72];   // W2^T bf16 (9.2 KB)
    __shared__ __align__(16) unsigned short lA[32 * 72];   // A tile bf16 (4.6 KB)
    __shared__ __align__(16) float lC[32 * 65];            // epilogue (8.3 KB)
    const int tid  = threadIdx.x;
    const int lane = tid & 63;
    const int wave = tid >> 6;
    const int g = lane >> 3;     // node slot within wave (0..7)
    const int l = lane & 7;      // feature lane: floats 8l..8l+7
    const int row0 = blockIdx.x * 32;
    const int n = row0 + wave * 8 + g;
    const bool valid = (n < n_nodes);
    const char* sp = (const char*)sin;
    const int SENTB = n_nodes << 7;   // sentinel zero row (byte offset)

    // stage W2^T (bf16) while gather loads are in flight
#pragma unroll
    for (int i = 0; i < 2; ++i) {
        int idx = tid + i * 256;   // 0..511
        int nn = idx >> 3;
        int c8 = idx & 7;
        uint4 u = *(const uint4*)(Wt2 + (size_t)nn * 64 + c8 * 8);
        *(uint4*)(lW + nn * 72 + c8 * 8) = u;
    }

    int rs = 0, re = 0;
    if (valid) { rs = row_start[n]; re = row_start[n + 1]; }

    // init acc with the self row (sentinel for invalid slots)
    uint4 us = *(const uint4*)(sp + (size_t)(valid ? (n << 7) : SENTB) + l * 16);
    float acc0 = bflo(us.x), acc1 = bfhi(us.x);
    float acc2 = bflo(us.y), acc3 = bfhi(us.y);
    float acc4 = bflo(us.z), acc5 = bfhi(us.z);
    float acc6 = bflo(us.w), acc7 = bfhi(us.w);

    for (int base = rs; base < re; base += 16) {
        int p0 = base + l;
        int p1 = base + 8 + l;
        int a0 = (p0 < re) ? csr[p0] : SENTB;
        int a1 = (p1 < re) ? csr[p1] : SENTB;
#pragma unroll
        for (int j = 0; j < 8; ++j) {
            int ab = __shfl(a0, g * 8 + j, 64);
            uint4 u = *(const uint4*)(sp + (size_t)(unsigned)ab + l * 16);
            acc0 += bflo(u.x); acc1 += bfhi(u.x);
            acc2 += bflo(u.y); acc3 += bfhi(u.y);
            acc4 += bflo(u.z); acc5 += bfhi(u.z);
            acc6 += bflo(u.w); acc7 += bfhi(u.w);
        }
#pragma unroll
        for (int j = 0; j < 8; ++j) {
            int ab = __shfl(a1, g * 8 + j, 64);
            uint4 u = *(const uint4*)(sp + (size_t)(unsigned)ab + l * 16);
            acc0 += bflo(u.x); acc1 += bfhi(u.x);
            acc2 += bflo(u.y); acc3 += bfhi(u.y);
            acc4 += bflo(u.z); acc5 += bfhi(u.z);
            acc6 += bflo(u.w); acc7 += bfhi(u.w);
        }
    }
    // finalize: v = relu(d*acc + b1), pack bf16 into the A-tile
    {
        float d = valid ? dinv[n] : 0.f;
        const float4 bA = ((const float4*)b1)[2 * l];
        const float4 bB = ((const float4*)b1)[2 * l + 1];
        float t0 = d * acc0, t1 = d * acc1, t2 = d * acc2, t3 = d * acc3;
        float t4 = d * acc4, t5 = d * acc5, t6 = d * acc6, t7 = d * acc7;
        float v0 = fmaxf(t0 + bA.x, 0.f), v1 = fmaxf(t1 + bA.y, 0.f);
        float v2 = fmaxf(t2 + bA.z, 0.f), v3 = fmaxf(t3 + bA.w, 0.f);
        float v4 = fmaxf(t4 + bB.x, 0.f), v5 = fmaxf(t5 + bB.y, 0.f);
        float v6 = fmaxf(t6 + bB.z, 0.f), v7 = fmaxf(t7 + bB.w, 0.f);
        unsigned q0 = (unsigned)f2bf(v0) | ((unsigned)f2bf(v1) << 16);
        unsigned q1 = (unsigned)f2bf(v2) | ((unsigned)f2bf(v3) << 16);
        unsigned q2 = (unsigned)f2bf(v4) | ((unsigned)f2bf(v5) << 16);
        unsigned q3 = (unsigned)f2bf(v6) | ((unsigned)f2bf(v7) << 16);
        int r = wave * 8 + g;
        *(uint4*)(lA + r * 72 + l * 8) = make_uint4(q0, q1, q2, q3);
    }
    __syncthreads();
    // MFMA: M=32 (2 tiles) x N=64 (4 tiles) x K=64, 2 C-tiles per wave
    {
        const int m16  = lane & 15;
        const int quad = lane >> 4;
        const int mt  = wave >> 1;
        const int nt0 = (wave & 1) * 2;
        v4f c0 = (v4f){0.f, 0.f, 0.f, 0.f};
        v4f c1 = (v4f){0.f, 0.f, 0.f, 0.f};
#pragma unroll
        for (int kk = 0; kk < 64; kk += 32) {
            v8s a  = *(const v8s*)(lA + (mt * 16 + m16) * 72 + kk + quad * 8);
            v8s b0 = *(const v8s*)(lW + (nt0 * 16 + m16) * 72 + kk + quad * 8);
            v8s b1v = *(const v8s*)(lW + ((nt0 + 1) * 16 + m16) * 72 + kk + quad * 8);
            c0 = __builtin_amdgcn_mfma_f32_16x16x32_bf16(a, b0, c0, 0, 0, 0);
            c1 = __builtin_amdgcn_mfma_f32_16x16x32_bf16(a, b1v, c1, 0, 0, 0);
        }
#pragma unroll
        for (int r = 0; r < 4; ++r) {
            int rowt = mt * 16 + quad * 4 + r;
            lC[rowt * 65 + nt0 * 16 + m16]       = c0[r];
            lC[rowt * 65 + (nt0 + 1) * 16 + m16] = c1[r];
        }
    }
    __syncthreads();
    // coalesced epilogue: 32 rows x 64 cols, dinv scale, bf16 store
    {
        int base = tid * 8;
        int r = base >> 6;
        int c = base & 63;
        int gr = row0 + r;
        if (gr < n_nodes) {
            float d = dinv[gr];
            const float* p = lC + r * 65 + c;
            unsigned p0 = (unsigned)f2bf(p[0] * d) | ((unsigned)f2bf(p[1] * d) << 16);
            unsigned p1 = (unsigned)f2bf(p[2] * d) | ((unsigned)f2bf(p[3] * d) << 16);
            unsigned p2 = (unsigned)f2bf(p[4] * d) | ((unsigned)f2bf(p[5] * d) << 16);
            unsigned p3 = (unsigned)f2bf(p[6] * d) | ((unsigned)f2bf(p[7] * d) << 16);
            *(uint4*)(sout + (size_t)gr * 64 + c) = make_uint4(p0, p1, p2, p3);
        }
    }
}

// ---------------- layer2: 8-lane-group gather + Wfc dot + pool -------------
__launch_bounds__(256)
__global__ void k_layer2pool(const unsigned short* __restrict__ sin, const int* __restrict__ row_start,
                             const int* __restrict__ csr, const float* __restrict__ b2,
                             const float* __restrict__ dinv, const float* __restrict__ Wfc,
                             const int* __restrict__ batch,
                             float* gsum, int* gcnt, int n_nodes) {
    __shared__ float lsum[256];
    __shared__ int   lcnt[256];
    const int tid = threadIdx.x;
    lsum[tid] = 0.f; lcnt[tid] = 0;
    __syncthreads();
    const int lane = tid & 63;
    const int wave = tid >> 6;
    const int g = lane >> 3;
    const int l = lane & 7;
    const int n = (blockIdx.x * 4 + wave) * 8 + g;
    const bool valid = (n < n_nodes);
    const char* sp = (const char*)sin;
    const int SENTB = n_nodes << 7;

    int rs = 0, re = 0;
    if (valid) { rs = row_start[n]; re = row_start[n + 1]; }

    uint4 us = *(const uint4*)(sp + (size_t)(valid ? (n << 7) : SENTB) + l * 16);
    float acc0 = bflo(us.x), acc1 = bfhi(us.x);
    float acc2 = bflo(us.y), acc3 = bfhi(us.y);
    float acc4 = bflo(us.z), acc5 = bfhi(us.z);
    float acc6 = bflo(us.w), acc7 = bfhi(us.w);

    for (int base = rs; base < re; base += 16) {
        int p0 = base + l;
        int p1 = base + 8 + l;
        int a0 = (p0 < re) ? csr[p0] : SENTB;
        int a1 = (p1 < re) ? csr[p1] : SENTB;
#pragma unroll
        for (int j = 0; j < 8; ++j) {
            int ab = __shfl(a0, g * 8 + j, 64);
            uint4 u = *(const uint4*)(sp + (size_t)(unsigned)ab + l * 16);
            acc0 += bflo(u.x); acc1 += bfhi(u.x);
            acc2 += bflo(u.y); acc3 += bfhi(u.y);
            acc4 += bflo(u.z); acc5 += bfhi(u.z);
            acc6 += bflo(u.w); acc7 += bfhi(u.w);
        }
#pragma unroll
        for (int j = 0; j < 8; ++j) {
            int ab = __shfl(a1, g * 8 + j, 64);
            uint4 u = *(const uint4*)(sp + (size_t)(unsigned)ab + l * 16);
            acc0 += bflo(u.x); acc1 += bfhi(u.x);
            acc2 += bflo(u.y); acc3 += bfhi(u.y);
            acc4 += bflo(u.z); acc5 += bfhi(u.z);
            acc6 += bflo(u.w); acc7 += bfhi(u.w);
        }
    }
    float d = dinv[valid ? n : 0];
    const float4 bA  = ((const float4*)b2)[2 * l];
    const float4 bB  = ((const float4*)b2)[2 * l + 1];
    const float4 wA  = ((const float4*)Wfc)[2 * l];
    const float4 wB  = ((const float4*)Wfc)[2 * l + 1];
    float t = fmaxf(fmaf(d, acc0, bA.x), 0.f) * wA.x
            + fmaxf(fmaf(d, acc1, bA.y), 0.f) * wA.y
            + fmaxf(fmaf(d, acc2, bA.z), 0.f) * wA.z
            + fmaxf(fmaf(d, acc3, bA.w), 0.f) * wA.w
            + fmaxf(fmaf(d, acc4, bB.x), 0.f) * wB.x
            + fmaxf(fmaf(d, acc5, bB.y), 0.f) * wB.y
            + fmaxf(fmaf(d, acc6, bB.z), 0.f) * wB.z
            + fmaxf(fmaf(d, acc7, bB.w), 0.f) * wB.w;
    // 8-lane tree within the group (shared shuffle instrs across 8 groups)
#pragma unroll
    for (int off = 4; off; off >>= 1) t += __shfl_down(t, off, 8);
    if (l == 0 && valid) {
        int gr = batch[n];
        atomicAdd(&lsum[gr], t);
        atomicAdd(&lcnt[gr], 1);
    }
    __syncthreads();
    if (lcnt[tid]) {
        atomicAdd(&gsum[tid], lsum[tid]);
        atomicAdd(&gcnt[tid], lcnt[tid]);
    }
}

__global__ void k_out(const float* __restrict__ gsum, const int* __restrict__ gcnt,
                      const float* __restrict__ bfc, float* out) {
    int g = threadIdx.x;
    if (g < 256) {
        float c = (float)(gcnt[g] > 1 ? gcnt[g] : 1);
        out[g] = gsum[g] / c + bfc[0];
    }
}

// ---------------------------------------------------------------------------
extern "C" void kernel_launch(void* const* d_in, const int* in_sizes, int n_in,
                              void* d_out, int out_size, void* d_ws, size_t ws_size,
                              hipStream_t stream) {
    const float* x   = (const float*)d_in[0];
    const int*   ei  = (const int*)d_in[1];
    const int*   bat = (const int*)d_in[2];
    const float* W1  = (const float*)d_in[3];
    const float* b1  = (const float*)d_in[4];
    const float* W2  = (const float*)d_in[5];
    const float* b2  = (const float*)d_in[6];
    const float* Wfc = (const float*)d_in[7];
    const float* bfc = (const float*)d_in[8];
    float* out = (float*)d_out;

    const int n_nodes = in_sizes[2];
    const int n_edges = in_sizes[1] / 2;
    const int* src = ei;
    const int* dst = ei + n_edges;
    const int NBUCK = (n_nodes + 127) >> 7;

    char* w = (char*)d_ws;
    size_t off = 0;
    auto alloc = [&](size_t bytes) -> void* {
        void* p = w + off;
        off += (bytes + 255) & ~(size_t)255;
        return p;
    };
    float* dinv = (float*)alloc((size_t)n_nodes * sizeof(float));
    unsigned short* bufA = (unsigned short*)alloc(((size_t)n_nodes + 1) * HIDDEN * 2);
    unsigned short* bufB = (unsigned short*)alloc(((size_t)n_nodes + 1) * HIDDEN * 2);
    unsigned short* Wt   = (unsigned short*)alloc((size_t)HIDDEN * IN_DIM * 2);
    unsigned short* Wt2  = (unsigned short*)alloc((size_t)HIDDEN * HIDDEN * 2);
    float* gsum = (float*)alloc(256 * sizeof(float));
    int*   gcnt = (int*)  alloc(256 * sizeof(int));
    int*   cursor      = (int*)alloc((size_t)NB_MAX * sizeof(int));
    int*   bucket_base = (int*)alloc((size_t)NB_MAX * sizeof(int));
    unsigned* bucket_data = (unsigned*)alloc((size_t)NB_MAX * CAP * sizeof(unsigned));
    int* row_start = (int*)alloc(((size_t)n_nodes + 1) * sizeof(int));
    int* csr       = (int*)alloc(((size_t)n_edges + 64) * sizeof(int));
    (void)ws_size; (void)n_in; (void)out_size;

    hipLaunchKernelGGL(k_init, dim3(NB_MAX / 256), dim3(256), 0, stream,
                       cursor, gsum, gcnt, bufA, bufB, n_nodes);
    hipLaunchKernelGGL(k_bin, dim3((n_edges + 4095) / 4096), dim3(256), 0, stream,
                       src, dst, cursor, bucket_data, n_edges);
    hipLaunchKernelGGL(k_bexc, dim3(1), dim3(256), 0, stream,
                       cursor, bucket_base, row_start, n_nodes, NBUCK);
    hipLaunchKernelGGL(k_csr, dim3(NBUCK), dim3(256), 0, stream,
                       bucket_data, cursor, bucket_base, row_start, csr, dinv, n_nodes);
    hipLaunchKernelGGL(k_prep, dim3((HIDDEN * IN_DIM + HIDDEN * HIDDEN) / 256), dim3(256), 0, stream,
                       W1, W2, Wt, Wt2);
    hipLaunchKernelGGL(k_gemm1m, dim3((n_nodes + 63) / 64), dim3(256), 0, stream,
                       x, Wt, dinv, bufA, n_nodes);
    hipLaunchKernelGGL(k_agg1g2, dim3((n_nodes + 31) / 32), dim3(256), 0, stream,
                       bufA, row_start, csr, dinv, Wt2, b1, bufB, n_nodes);
    hipLaunchKernelGGL(k_layer2pool, dim3((n_nodes + 31) / 32), dim3(256), 0, stream,
                       bufB, row_start, csr, b2, dinv, Wfc, bat, gsum, gcnt, n_nodes);
    hipLaunchKernelGGL(k_out, dim3(1), dim3(256), 0, stream, gsum, gcnt, bfc, out);
}